// Round 1
// baseline (20604.051 us; speedup 1.0000x reference)
//
#include <hip/hip_runtime.h>
#include <hip/hip_cooperative_groups.h>

namespace cg = cooperative_groups;

#define TXN 256   // Tx
#define NA 256    // n_a
#define NF 128    // features
#define NS 512    // n_s
#define TYN 10
#define VOCAB 1024

__device__ __forceinline__ float fsigmoid(float x) { return 1.f / (1.f + __expf(-x)); }
__device__ __forceinline__ float ftanh(float x)    { return 1.f - 2.f / (1.f + __expf(2.f * x)); }

// ---------------------------------------------------------------------------
// Persistent bidirectional LSTM encoder.
// Grid: 256 blocks x 256 threads, cooperative (grid.sync per timestep).
// dir = blockIdx & 1. Per dir: 128 blocks = 8 i-tiles(32 rows) x 16 j-tiles(16 units).
// Thread owns 2 hidden units (2 rows x 1 j), 4 gates each -> 8 accumulators.
// c kept in registers for all 256 steps; h written to / read from `a`.
// a layout: (m, Tx, 512) with cols [0:256)=fwd, [256:512)=bwd.
// ---------------------------------------------------------------------------
__global__ __launch_bounds__(256, 1) void encoder_kernel(
    const float* __restrict__ X,
    const float* __restrict__ Wih_f, const float* __restrict__ Whh_f, const float* __restrict__ b_f,
    const float* __restrict__ Wih_b, const float* __restrict__ Whh_b, const float* __restrict__ b_b,
    float* __restrict__ a)
{
    __shared__ float As[32][392];   // [h(256) | x(128)] rows, padded
    __shared__ float Ws[64][36];    // 64 gate rows x 32 k-chunk, padded
    __shared__ float bs[64];

    const int tid = threadIdx.x;
    const int dir = blockIdx.x & 1;
    const int bid = blockIdx.x >> 1;   // 0..127
    const int i0 = (bid >> 4) * 32;    // 8 i-tiles
    const int j0 = (bid & 15) * 16;    // 16 j-tiles

    const float* __restrict__ Wih = dir ? Wih_b : Wih_f;
    const float* __restrict__ Whh = dir ? Whh_b : Whh_f;
    const float* __restrict__ bv  = dir ? b_b  : b_f;

    const int jl = tid & 15;     // unit within j-tile
    const int ip = tid >> 4;     // 0..15
    const int iA = ip * 2;       // local row (even)

    if (tid < 64) {
        int g = tid >> 4, j = tid & 15;
        bs[tid] = bv[g * NA + j0 + j];
    }

    float c0 = 0.f, c1 = 0.f;
    cg::grid_group grid = cg::this_grid();

    for (int step = 0; step < TXN; ++step) {
        const int t = dir ? (TXN - 1 - step) : step;

        // ---- stage A panel: h(prev) | x(t) ----
        if (step == 0) {
            #pragma unroll 4
            for (int r = 0; r < 32; ++r) As[r][tid] = 0.f;
        } else {
            const int tprev = dir ? (t + 1) : (t - 1);
            #pragma unroll 4
            for (int r = 0; r < 32; ++r) {
                As[r][tid] = a[(((size_t)(i0 + r) * TXN + tprev) << 9) + dir * NA + tid];
            }
        }
        {
            const int kx = tid & 127;
            const int rbase = tid >> 7;   // 0..1
            #pragma unroll 4
            for (int rr = 0; rr < 16; ++rr) {
                int r = rr * 2 + rbase;
                As[r][256 + kx] = X[((size_t)(i0 + r) * TXN + t) * NF + kx];
            }
        }
        __syncthreads();

        float acc[2][4] = {{0.f,0.f,0.f,0.f},{0.f,0.f,0.f,0.f}};

        for (int kb = 0; kb < 12; ++kb) {
            // stage weight k-chunk: 64 rows x 32 cols
            {
                const int kk = tid & 31;
                const int rb = tid >> 5;   // 0..7
                #pragma unroll
                for (int rr = 0; rr < 8; ++rr) {
                    int r = rr * 8 + rb;
                    int row = (r >> 4) * NA + j0 + (r & 15);
                    float w;
                    if (kb < 8) w = Whh[row * NA + kb * 32 + kk];
                    else        w = Wih[row * NF + (kb - 8) * 32 + kk];
                    Ws[r][kk] = w;
                }
            }
            __syncthreads();
            const int kabs = kb * 32;
            #pragma unroll
            for (int k4 = 0; k4 < 32; k4 += 4) {
                float4 a0 = *(const float4*)&As[iA][kabs + k4];
                float4 a1 = *(const float4*)&As[iA + 1][kabs + k4];
                #pragma unroll
                for (int g = 0; g < 4; ++g) {
                    float4 w = *(const float4*)&Ws[g * 16 + jl][k4];
                    acc[0][g] += a0.x*w.x + a0.y*w.y + a0.z*w.z + a0.w*w.w;
                    acc[1][g] += a1.x*w.x + a1.y*w.y + a1.z*w.z + a1.w*w.w;
                }
            }
            __syncthreads();
        }

        // gates, state update, write h into a
        float h0, h1;
        {
            float gi = fsigmoid(acc[0][0] + bs[jl]);
            float gf = fsigmoid(acc[0][1] + bs[16 + jl]);
            float gg = ftanh  (acc[0][2] + bs[32 + jl]);
            float go = fsigmoid(acc[0][3] + bs[48 + jl]);
            c0 = gf * c0 + gi * gg;
            h0 = go * ftanh(c0);
        }
        {
            float gi = fsigmoid(acc[1][0] + bs[jl]);
            float gf = fsigmoid(acc[1][1] + bs[16 + jl]);
            float gg = ftanh  (acc[1][2] + bs[32 + jl]);
            float go = fsigmoid(acc[1][3] + bs[48 + jl]);
            c1 = gf * c1 + gi * gg;
            h1 = go * ftanh(c1);
        }
        a[(((size_t)(i0 + iA)     * TXN + t) << 9) + dir * NA + j0 + jl] = h0;
        a[(((size_t)(i0 + iA + 1) * TXN + t) << 9) + dir * NA + j0 + jl] = h1;

        __threadfence();
        grid.sync();
    }
}

// ---------------------------------------------------------------------------
// Generic tiled GEMM: C[M,N] = A[M,K] @ B[N,K]^T + bias[N]
// 64x64 tile, BK=16, 256 threads, 4x4 per thread. M must be multiple of 64,
// K multiple of 16. N masked.
// ---------------------------------------------------------------------------
__global__ __launch_bounds__(256) void gemm_bt(
    const float* __restrict__ A, int lda,
    const float* __restrict__ B, int ldb,
    const float* __restrict__ bias,
    float* __restrict__ C, int ldc,
    int N, int K)
{
    __shared__ float As[16][72];
    __shared__ float Bs[16][72];
    const int tid = threadIdx.x;
    const int i0 = blockIdx.x * 64;
    const int j0 = blockIdx.y * 64;
    const int tx = tid & 15, ty = tid >> 4;
    const int m  = tid >> 2;          // 0..63
    const int k4 = (tid & 3) * 4;

    float acc[4][4] = {};
    for (int kb = 0; kb < K; kb += 16) {
        float4 va = *(const float4*)&A[(size_t)(i0 + m) * lda + kb + k4];
        float4 vb;
        if (j0 + m < N) vb = *(const float4*)&B[(size_t)(j0 + m) * ldb + kb + k4];
        else            vb = make_float4(0.f, 0.f, 0.f, 0.f);
        __syncthreads();
        As[k4+0][m] = va.x; As[k4+1][m] = va.y; As[k4+2][m] = va.z; As[k4+3][m] = va.w;
        Bs[k4+0][m] = vb.x; Bs[k4+1][m] = vb.y; Bs[k4+2][m] = vb.z; Bs[k4+3][m] = vb.w;
        __syncthreads();
        #pragma unroll
        for (int k = 0; k < 16; ++k) {
            float4 a4 = *(const float4*)&As[k][ty * 4];
            float4 b4 = *(const float4*)&Bs[k][tx * 4];
            acc[0][0] += a4.x*b4.x; acc[0][1] += a4.x*b4.y; acc[0][2] += a4.x*b4.z; acc[0][3] += a4.x*b4.w;
            acc[1][0] += a4.y*b4.x; acc[1][1] += a4.y*b4.y; acc[1][2] += a4.y*b4.z; acc[1][3] += a4.y*b4.w;
            acc[2][0] += a4.z*b4.x; acc[2][1] += a4.z*b4.y; acc[2][2] += a4.z*b4.z; acc[2][3] += a4.z*b4.w;
            acc[3][0] += a4.w*b4.x; acc[3][1] += a4.w*b4.y; acc[3][2] += a4.w*b4.z; acc[3][3] += a4.w*b4.w;
        }
    }
    #pragma unroll
    for (int r = 0; r < 4; ++r) {
        int row = i0 + ty * 4 + r;
        #pragma unroll
        for (int c = 0; c < 4; ++c) {
            int col = j0 + tx * 4 + c;
            if (col < N) {
                float v = acc[r][c] + (bias ? bias[col] : 0.f);
                C[(size_t)row * ldc + col] = v;
            }
        }
    }
}

// ---------------------------------------------------------------------------
// Fused attention: block per batch row i.
// scores -> softmax over Tx -> context written into xcat[:, 0:512].
// ---------------------------------------------------------------------------
__global__ __launch_bounds__(256) void attn_kernel(
    const float* __restrict__ aW1,   // (m*Tx, 10), b1 already added
    const float* __restrict__ sW1,   // (m, 10)
    const float* __restrict__ W2,    // (10,)
    const float* __restrict__ b2,    // (1,)
    const float* __restrict__ a,     // (m, Tx, 512)
    float* __restrict__ xcat)        // (m, 1024)
{
    __shared__ float sh_s[10];
    __shared__ float sh_w2[10];
    __shared__ float red[256];
    __shared__ float al[256];
    const int i = blockIdx.x;
    const int tid = threadIdx.x;
    if (tid < 10) { sh_s[tid] = sW1[i * 10 + tid]; sh_w2[tid] = W2[tid]; }
    __syncthreads();

    float sum = b2[0];
    const float* ar = aW1 + ((size_t)i * TXN + tid) * 10;
    #pragma unroll
    for (int h = 0; h < 10; ++h) {
        float e = ftanh(ar[h] + sh_s[h]);
        sum += e * sh_w2[h];
    }
    float sc = fmaxf(sum, 0.f);

    red[tid] = sc;
    __syncthreads();
    for (int s = 128; s > 0; s >>= 1) {
        if (tid < s) red[tid] = fmaxf(red[tid], red[tid + s]);
        __syncthreads();
    }
    float mx = red[0];
    __syncthreads();
    float p = __expf(sc - mx);
    red[tid] = p;
    __syncthreads();
    for (int s = 128; s > 0; s >>= 1) {
        if (tid < s) red[tid] += red[tid + s];
        __syncthreads();
    }
    float inv = 1.f / red[0];
    al[tid] = p * inv;
    __syncthreads();

    float acc0 = 0.f, acc1 = 0.f;
    const float* arow = a + (size_t)i * TXN * NS;
    for (int t = 0; t < TXN; ++t) {
        float w = al[t];
        acc0 += w * arow[t * NS + tid];
        acc1 += w * arow[t * NS + 256 + tid];
    }
    xcat[(size_t)i * 1024 + tid]       = acc0;
    xcat[(size_t)i * 1024 + 256 + tid] = acc1;
}

// ---------------------------------------------------------------------------
// LSTM cell elementwise update from gate pre-activations.
// ---------------------------------------------------------------------------
__global__ __launch_bounds__(256) void cell_kernel(
    const float* __restrict__ g, float* __restrict__ c,
    float* __restrict__ s_buf, float* __restrict__ xcat)
{
    int idx = blockIdx.x * 256 + threadIdx.x;   // 256*512
    int i = idx >> 9, j = idx & 511;
    const float* gr = g + (size_t)i * 2048;
    float gi = fsigmoid(gr[j]);
    float gf = fsigmoid(gr[512 + j]);
    float gg = ftanh  (gr[1024 + j]);
    float go = fsigmoid(gr[1536 + j]);
    float cn = gf * c[idx] + gi * gg;
    c[idx] = cn;
    float h = go * ftanh(cn);
    s_buf[idx] = h;
    xcat[(size_t)i * 1024 + 512 + j] = h;
}

// Concatenate decoder LSTM weights: Wcat[r] = [Wc_ih[r] | Wc_hh[r]]
__global__ __launch_bounds__(256) void wcat_kernel(
    const float* __restrict__ Wc_ih, const float* __restrict__ Wc_hh,
    float* __restrict__ Wcat)
{
    int idx = blockIdx.x * 256 + threadIdx.x;   // 2048*1024
    int r = idx >> 10, k = idx & 1023;
    Wcat[idx] = (k < 512) ? Wc_ih[(size_t)r * 512 + k] : Wc_hh[(size_t)r * 512 + (k - 512)];
}

extern "C" void kernel_launch(void* const* d_in, const int* in_sizes, int n_in,
                              void* d_out, int out_size, void* d_ws, size_t ws_size,
                              hipStream_t stream)
{
    const float* X     = (const float*)d_in[0];
    const float* Wih_f = (const float*)d_in[1];
    const float* Whh_f = (const float*)d_in[2];
    const float* b_f   = (const float*)d_in[3];
    const float* Wih_b = (const float*)d_in[4];
    const float* Whh_b = (const float*)d_in[5];
    const float* b_b   = (const float*)d_in[6];
    const float* W1    = (const float*)d_in[7];
    const float* b1    = (const float*)d_in[8];
    const float* W2    = (const float*)d_in[9];
    const float* b2    = (const float*)d_in[10];
    const float* Wc_ih = (const float*)d_in[11];
    const float* Wc_hh = (const float*)d_in[12];
    const float* bc    = (const float*)d_in[13];
    const float* Wfc   = (const float*)d_in[14];
    const float* bfc   = (const float*)d_in[15];
    float* out = (float*)d_out;
    float* ws  = (float*)d_ws;

    // workspace layout (float offsets)
    float* c_buf = ws;                    // 256*512
    float* s_buf = ws + 131072;           // 256*512
    float* xcat  = ws + 262144;           // 256*1024  [ctx | s]
    float* a     = ws + 524288;           // 256*256*512
    float* aW1   = ws + 34078720;         // 65536*10
    float* Wcat  = ws + 34734080;         // 2048*1024
    float* sW1   = ws + 36831232;         // 256*10
    float* g_buf = ws + 36833792;         // 256*2048
    // total: 37,358,080 floats = 149.4 MB

    // zero c, s, xcat (contiguous 2 MB)
    hipMemsetAsync(c_buf, 0, (size_t)524288 * sizeof(float), stream);

    wcat_kernel<<<8192, 256, 0, stream>>>(Wc_ih, Wc_hh, Wcat);

    // persistent bidirectional LSTM encoder (cooperative: grid.sync per step)
    {
        void* args[] = { (void*)&X, (void*)&Wih_f, (void*)&Whh_f, (void*)&b_f,
                         (void*)&Wih_b, (void*)&Whh_b, (void*)&b_b, (void*)&a };
        hipLaunchCooperativeKernel(reinterpret_cast<void*>(encoder_kernel),
                                   dim3(256), dim3(256), args, 0, stream);
    }

    // aW1 = a @ W1[:, :512]^T + b1   (loop-invariant across decoder steps)
    gemm_bt<<<dim3(1024, 1), 256, 0, stream>>>(a, 512, W1, 1024, b1, aW1, 10, 10, 512);

    for (int ty = 0; ty < TYN; ++ty) {
        // sW1 = s @ W1[:, 512:]^T
        gemm_bt<<<dim3(4, 1), 256, 0, stream>>>(s_buf, 512, W1 + 512, 1024, nullptr, sW1, 10, 10, 512);
        // attention + context -> xcat[:, :512]
        attn_kernel<<<256, 256, 0, stream>>>(aW1, sW1, W2, b2, a, xcat);
        // gates = xcat @ Wcat^T + bc
        gemm_bt<<<dim3(4, 32), 256, 0, stream>>>(xcat, 1024, Wcat, 1024, bc, g_buf, 2048, 2048, 1024);
        // cell update -> c, s (s also into xcat[:, 512:])
        cell_kernel<<<512, 256, 0, stream>>>(g_buf, c_buf, s_buf, xcat);
        // logits = s @ Wfc^T + bfc -> out[:, ty, :]
        gemm_bt<<<dim3(4, 16), 256, 0, stream>>>(s_buf, 512, Wfc, 512, bfc,
                                                 out + ty * VOCAB, TYN * VOCAB, VOCAB, 512);
    }
}

// Round 2
// 18540.495 us; speedup vs baseline: 1.1113x; 1.1113x over previous
//
#include <hip/hip_runtime.h>
#include <hip/hip_cooperative_groups.h>

namespace cg = cooperative_groups;

#define TXN 256   // Tx
#define NA 256    // n_a
#define NF 128    // features
#define NS 512    // n_s
#define TYN 10
#define VOCAB 1024

// LDS layout constants for encoder (floats)
#define WS_STRIDE 388          // 64 gate-rows x 384 k, padded (388%32==4 -> 2-way max)
#define AS_STRIDE 392          // 32 rows x 384 (h|x), padded
#define WS_FLOATS (64 * WS_STRIDE)                 // 24832
#define AS_FLOATS (32 * AS_STRIDE)                 // 12544
#define ENC_LDS_BYTES ((WS_FLOATS + AS_FLOATS + 64) * 4)   // 149,760 B

__device__ __forceinline__ float fsigmoid(float x) { return 1.f / (1.f + __expf(-x)); }
__device__ __forceinline__ float ftanh(float x)    { return 1.f - 2.f / (1.f + __expf(2.f * x)); }

// ---------------------------------------------------------------------------
// Persistent bidirectional LSTM encoder, weights resident in LDS.
// Grid: 256 blocks x 256 threads, cooperative (grid.sync per timestep).
// dir = blockIdx & 1. Per dir: 128 blocks = 8 i-tiles(32 rows) x 16 j-tiles(16 units).
// Thread owns 2 batch rows x 1 unit x 4 gates -> 8 accumulators.
// Weight slice (64 gate-rows x 384) loaded into LDS ONCE before the step loop.
// c kept in registers for all 256 steps; h written to / read from `a`.
// a layout: (m, Tx, 512) with cols [0:256)=fwd, [256:512)=bwd.
// ---------------------------------------------------------------------------
__global__ __launch_bounds__(256, 1) void encoder_kernel(
    const float* __restrict__ X,
    const float* __restrict__ Wih_f, const float* __restrict__ Whh_f, const float* __restrict__ b_f,
    const float* __restrict__ Wih_b, const float* __restrict__ Whh_b, const float* __restrict__ b_b,
    float* __restrict__ a)
{
    extern __shared__ float smem[];
    float* Wsh = smem;                       // [64][WS_STRIDE], k: 0..255 = Whh, 256..383 = Wih
    float* Ash = smem + WS_FLOATS;           // [32][AS_STRIDE], k: 0..255 = h, 256..383 = x
    float* bsh = smem + WS_FLOATS + AS_FLOATS;  // [64]

    const int tid = threadIdx.x;
    const int dir = blockIdx.x & 1;
    const int bid = blockIdx.x >> 1;   // 0..127
    const int i0 = (bid >> 4) * 32;    // 8 i-tiles
    const int j0 = (bid & 15) * 16;    // 16 j-tiles

    const float* __restrict__ Wih = dir ? Wih_b : Wih_f;
    const float* __restrict__ Whh = dir ? Whh_b : Whh_f;
    const float* __restrict__ bv  = dir ? b_b  : b_f;

    const int jl = tid & 15;     // unit within j-tile
    const int ip = tid >> 4;     // 0..15
    const int iA = ip * 2;       // local batch row (even)

    // ---- one-time: weights + bias into LDS ----
    if (tid < 64) {
        int g = tid >> 4, j = tid & 15;
        bsh[tid] = bv[g * NA + j0 + j];
    }
    for (int r = 0; r < 64; ++r) {
        int row = (r >> 4) * NA + j0 + (r & 15);
        Wsh[r * WS_STRIDE + tid] = Whh[(size_t)row * NA + tid];
        if (tid < NF) Wsh[r * WS_STRIDE + 256 + tid] = Wih[(size_t)row * NF + tid];
    }

    float c0 = 0.f, c1 = 0.f;
    cg::grid_group grid = cg::this_grid();

    const float* W0 = Wsh + (size_t)jl * WS_STRIDE;            // gate i
    const float* W1 = W0 + 16 * WS_STRIDE;                     // gate f
    const float* W2 = W0 + 32 * WS_STRIDE;                     // gate g
    const float* W3 = W0 + 48 * WS_STRIDE;                     // gate o
    const float* A0 = Ash + (size_t)iA * AS_STRIDE;
    const float* A1 = A0 + AS_STRIDE;

    for (int step = 0; step < TXN; ++step) {
        const int t = dir ? (TXN - 1 - step) : step;

        // ---- stage A panel: h(prev) | x(t) ----
        if (step == 0) {
            #pragma unroll 4
            for (int r = 0; r < 32; ++r) Ash[r * AS_STRIDE + tid] = 0.f;
        } else {
            const int tprev = dir ? (t + 1) : (t - 1);
            #pragma unroll 4
            for (int r = 0; r < 32; ++r) {
                Ash[r * AS_STRIDE + tid] =
                    a[(((size_t)(i0 + r) * TXN + tprev) << 9) + dir * NA + tid];
            }
        }
        {
            const int kx = tid & 127;
            const int rbase = tid >> 7;   // 0..1
            #pragma unroll 4
            for (int rr = 0; rr < 16; ++rr) {
                int r = rr * 2 + rbase;
                Ash[r * AS_STRIDE + 256 + kx] = X[((size_t)(i0 + r) * TXN + t) * NF + kx];
            }
        }
        __syncthreads();

        float acc[2][4] = {{0.f,0.f,0.f,0.f},{0.f,0.f,0.f,0.f}};

        #pragma unroll 8
        for (int k4 = 0; k4 < 384; k4 += 4) {
            float4 a0 = *(const float4*)&A0[k4];
            float4 a1 = *(const float4*)&A1[k4];
            float4 w0 = *(const float4*)&W0[k4];
            float4 w1 = *(const float4*)&W1[k4];
            float4 w2 = *(const float4*)&W2[k4];
            float4 w3 = *(const float4*)&W3[k4];
            acc[0][0] += a0.x*w0.x + a0.y*w0.y + a0.z*w0.z + a0.w*w0.w;
            acc[0][1] += a0.x*w1.x + a0.y*w1.y + a0.z*w1.z + a0.w*w1.w;
            acc[0][2] += a0.x*w2.x + a0.y*w2.y + a0.z*w2.z + a0.w*w2.w;
            acc[0][3] += a0.x*w3.x + a0.y*w3.y + a0.z*w3.z + a0.w*w3.w;
            acc[1][0] += a1.x*w0.x + a1.y*w0.y + a1.z*w0.z + a1.w*w0.w;
            acc[1][1] += a1.x*w1.x + a1.y*w1.y + a1.z*w1.z + a1.w*w1.w;
            acc[1][2] += a1.x*w2.x + a1.y*w2.y + a1.z*w2.z + a1.w*w2.w;
            acc[1][3] += a1.x*w3.x + a1.y*w3.y + a1.z*w3.z + a1.w*w3.w;
        }

        // gates, state update, write h into a
        float h0, h1;
        {
            float gi = fsigmoid(acc[0][0] + bsh[jl]);
            float gf = fsigmoid(acc[0][1] + bsh[16 + jl]);
            float gg = ftanh  (acc[0][2] + bsh[32 + jl]);
            float go = fsigmoid(acc[0][3] + bsh[48 + jl]);
            c0 = gf * c0 + gi * gg;
            h0 = go * ftanh(c0);
        }
        {
            float gi = fsigmoid(acc[1][0] + bsh[jl]);
            float gf = fsigmoid(acc[1][1] + bsh[16 + jl]);
            float gg = ftanh  (acc[1][2] + bsh[32 + jl]);
            float go = fsigmoid(acc[1][3] + bsh[48 + jl]);
            c1 = gf * c1 + gi * gg;
            h1 = go * ftanh(c1);
        }
        a[(((size_t)(i0 + iA)     * TXN + t) << 9) + dir * NA + j0 + jl] = h0;
        a[(((size_t)(i0 + iA + 1) * TXN + t) << 9) + dir * NA + j0 + jl] = h1;

        __threadfence();
        grid.sync();
    }
}

// ---------------------------------------------------------------------------
// Generic tiled GEMM: C[M,N] = A[M,K] @ B[N,K]^T + bias[N]
// 64x64 tile, BK=16, 256 threads, 4x4 per thread. M must be multiple of 64,
// K multiple of 16. N masked.
// ---------------------------------------------------------------------------
__global__ __launch_bounds__(256) void gemm_bt(
    const float* __restrict__ A, int lda,
    const float* __restrict__ B, int ldb,
    const float* __restrict__ bias,
    float* __restrict__ C, int ldc,
    int N, int K)
{
    __shared__ float As[16][72];
    __shared__ float Bs[16][72];
    const int tid = threadIdx.x;
    const int i0 = blockIdx.x * 64;
    const int j0 = blockIdx.y * 64;
    const int tx = tid & 15, ty = tid >> 4;
    const int m  = tid >> 2;          // 0..63
    const int k4 = (tid & 3) * 4;

    float acc[4][4] = {};
    for (int kb = 0; kb < K; kb += 16) {
        float4 va = *(const float4*)&A[(size_t)(i0 + m) * lda + kb + k4];
        float4 vb;
        if (j0 + m < N) vb = *(const float4*)&B[(size_t)(j0 + m) * ldb + kb + k4];
        else            vb = make_float4(0.f, 0.f, 0.f, 0.f);
        __syncthreads();
        As[k4+0][m] = va.x; As[k4+1][m] = va.y; As[k4+2][m] = va.z; As[k4+3][m] = va.w;
        Bs[k4+0][m] = vb.x; Bs[k4+1][m] = vb.y; Bs[k4+2][m] = vb.z; Bs[k4+3][m] = vb.w;
        __syncthreads();
        #pragma unroll
        for (int k = 0; k < 16; ++k) {
            float4 a4 = *(const float4*)&As[k][ty * 4];
            float4 b4 = *(const float4*)&Bs[k][tx * 4];
            acc[0][0] += a4.x*b4.x; acc[0][1] += a4.x*b4.y; acc[0][2] += a4.x*b4.z; acc[0][3] += a4.x*b4.w;
            acc[1][0] += a4.y*b4.x; acc[1][1] += a4.y*b4.y; acc[1][2] += a4.y*b4.z; acc[1][3] += a4.y*b4.w;
            acc[2][0] += a4.z*b4.x; acc[2][1] += a4.z*b4.y; acc[2][2] += a4.z*b4.z; acc[2][3] += a4.z*b4.w;
            acc[3][0] += a4.w*b4.x; acc[3][1] += a4.w*b4.y; acc[3][2] += a4.w*b4.z; acc[3][3] += a4.w*b4.w;
        }
    }
    #pragma unroll
    for (int r = 0; r < 4; ++r) {
        int row = i0 + ty * 4 + r;
        #pragma unroll
        for (int c = 0; c < 4; ++c) {
            int col = j0 + tx * 4 + c;
            if (col < N) {
                float v = acc[r][c] + (bias ? bias[col] : 0.f);
                C[(size_t)row * ldc + col] = v;
            }
        }
    }
}

// ---------------------------------------------------------------------------
// Fused attention: block per batch row i.
// scores -> softmax over Tx -> context written into xcat[:, 0:512].
// ---------------------------------------------------------------------------
__global__ __launch_bounds__(256) void attn_kernel(
    const float* __restrict__ aW1,   // (m*Tx, 10), b1 already added
    const float* __restrict__ sW1,   // (m, 10)
    const float* __restrict__ W2,    // (10,)
    const float* __restrict__ b2,    // (1,)
    const float* __restrict__ a,     // (m, Tx, 512)
    float* __restrict__ xcat)        // (m, 1024)
{
    __shared__ float sh_s[10];
    __shared__ float sh_w2[10];
    __shared__ float red[256];
    __shared__ float al[256];
    const int i = blockIdx.x;
    const int tid = threadIdx.x;
    if (tid < 10) { sh_s[tid] = sW1[i * 10 + tid]; sh_w2[tid] = W2[tid]; }
    __syncthreads();

    float sum = b2[0];
    const float* ar = aW1 + ((size_t)i * TXN + tid) * 10;
    #pragma unroll
    for (int h = 0; h < 10; ++h) {
        float e = ftanh(ar[h] + sh_s[h]);
        sum += e * sh_w2[h];
    }
    float sc = fmaxf(sum, 0.f);

    red[tid] = sc;
    __syncthreads();
    for (int s = 128; s > 0; s >>= 1) {
        if (tid < s) red[tid] = fmaxf(red[tid], red[tid + s]);
        __syncthreads();
    }
    float mx = red[0];
    __syncthreads();
    float p = __expf(sc - mx);
    red[tid] = p;
    __syncthreads();
    for (int s = 128; s > 0; s >>= 1) {
        if (tid < s) red[tid] += red[tid + s];
        __syncthreads();
    }
    float inv = 1.f / red[0];
    al[tid] = p * inv;
    __syncthreads();

    float acc0 = 0.f, acc1 = 0.f;
    const float* arow = a + (size_t)i * TXN * NS;
    for (int t = 0; t < TXN; ++t) {
        float w = al[t];
        acc0 += w * arow[t * NS + tid];
        acc1 += w * arow[t * NS + 256 + tid];
    }
    xcat[(size_t)i * 1024 + tid]       = acc0;
    xcat[(size_t)i * 1024 + 256 + tid] = acc1;
}

// ---------------------------------------------------------------------------
// LSTM cell elementwise update from gate pre-activations.
// ---------------------------------------------------------------------------
__global__ __launch_bounds__(256) void cell_kernel(
    const float* __restrict__ g, float* __restrict__ c,
    float* __restrict__ s_buf, float* __restrict__ xcat)
{
    int idx = blockIdx.x * 256 + threadIdx.x;   // 256*512
    int i = idx >> 9, j = idx & 511;
    const float* gr = g + (size_t)i * 2048;
    float gi = fsigmoid(gr[j]);
    float gf = fsigmoid(gr[512 + j]);
    float gg = ftanh  (gr[1024 + j]);
    float go = fsigmoid(gr[1536 + j]);
    float cn = gf * c[idx] + gi * gg;
    c[idx] = cn;
    float h = go * ftanh(cn);
    s_buf[idx] = h;
    xcat[(size_t)i * 1024 + 512 + j] = h;
}

// Concatenate decoder LSTM weights: Wcat[r] = [Wc_ih[r] | Wc_hh[r]]
__global__ __launch_bounds__(256) void wcat_kernel(
    const float* __restrict__ Wc_ih, const float* __restrict__ Wc_hh,
    float* __restrict__ Wcat)
{
    int idx = blockIdx.x * 256 + threadIdx.x;   // 2048*1024
    int r = idx >> 10, k = idx & 1023;
    Wcat[idx] = (k < 512) ? Wc_ih[(size_t)r * 512 + k] : Wc_hh[(size_t)r * 512 + (k - 512)];
}

extern "C" void kernel_launch(void* const* d_in, const int* in_sizes, int n_in,
                              void* d_out, int out_size, void* d_ws, size_t ws_size,
                              hipStream_t stream)
{
    const float* X     = (const float*)d_in[0];
    const float* Wih_f = (const float*)d_in[1];
    const float* Whh_f = (const float*)d_in[2];
    const float* b_f   = (const float*)d_in[3];
    const float* Wih_b = (const float*)d_in[4];
    const float* Whh_b = (const float*)d_in[5];
    const float* b_b   = (const float*)d_in[6];
    const float* W1    = (const float*)d_in[7];
    const float* b1    = (const float*)d_in[8];
    const float* W2    = (const float*)d_in[9];
    const float* b2    = (const float*)d_in[10];
    const float* Wc_ih = (const float*)d_in[11];
    const float* Wc_hh = (const float*)d_in[12];
    const float* bc    = (const float*)d_in[13];
    const float* Wfc   = (const float*)d_in[14];
    const float* bfc   = (const float*)d_in[15];
    float* out = (float*)d_out;
    float* ws  = (float*)d_ws;

    // workspace layout (float offsets)
    float* c_buf = ws;                    // 256*512
    float* s_buf = ws + 131072;           // 256*512
    float* xcat  = ws + 262144;           // 256*1024  [ctx | s]
    float* a     = ws + 524288;           // 256*256*512
    float* aW1   = ws + 34078720;         // 65536*10
    float* Wcat  = ws + 34734080;         // 2048*1024
    float* sW1   = ws + 36831232;         // 256*10
    float* g_buf = ws + 36833792;         // 256*2048
    // total: 37,358,080 floats = 149.4 MB

    // allow >64KB dynamic LDS for the encoder (idempotent, host-side; capture-safe)
    static int lds_raised = 0;
    if (!lds_raised) {
        hipFuncSetAttribute(reinterpret_cast<const void*>(encoder_kernel),
                            hipFuncAttributeMaxDynamicSharedMemorySize, ENC_LDS_BYTES);
        lds_raised = 1;
    }

    // zero c, s, xcat (contiguous 2 MB)
    hipMemsetAsync(c_buf, 0, (size_t)524288 * sizeof(float), stream);

    wcat_kernel<<<8192, 256, 0, stream>>>(Wc_ih, Wc_hh, Wcat);

    // persistent bidirectional LSTM encoder (cooperative: grid.sync per step)
    {
        void* args[] = { (void*)&X, (void*)&Wih_f, (void*)&Whh_f, (void*)&b_f,
                         (void*)&Wih_b, (void*)&Whh_b, (void*)&b_b, (void*)&a };
        hipLaunchCooperativeKernel(reinterpret_cast<void*>(encoder_kernel),
                                   dim3(256), dim3(256), args, ENC_LDS_BYTES, stream);
    }

    // aW1 = a @ W1[:, :512]^T + b1   (loop-invariant across decoder steps)
    gemm_bt<<<dim3(1024, 1), 256, 0, stream>>>(a, 512, W1, 1024, b1, aW1, 10, 10, 512);

    for (int ty = 0; ty < TYN; ++ty) {
        // sW1 = s @ W1[:, 512:]^T
        gemm_bt<<<dim3(4, 1), 256, 0, stream>>>(s_buf, 512, W1 + 512, 1024, nullptr, sW1, 10, 10, 512);
        // attention + context -> xcat[:, :512]
        attn_kernel<<<256, 256, 0, stream>>>(aW1, sW1, W2, b2, a, xcat);
        // gates = xcat @ Wcat^T + bc
        gemm_bt<<<dim3(4, 32), 256, 0, stream>>>(xcat, 1024, Wcat, 1024, bc, g_buf, 2048, 2048, 1024);
        // cell update -> c, s (s also into xcat[:, 512:])
        cell_kernel<<<512, 256, 0, stream>>>(g_buf, c_buf, s_buf, xcat);
        // logits = s @ Wfc^T + bfc -> out[:, ty, :]
        gemm_bt<<<dim3(4, 16), 256, 0, stream>>>(s_buf, 512, Wfc, 512, bfc,
                                                 out + ty * VOCAB, TYN * VOCAB, VOCAB, 512);
    }
}

// Round 3
// 7328.674 us; speedup vs baseline: 2.8114x; 2.5299x over previous
//
#include <hip/hip_runtime.h>
#include <hip/hip_cooperative_groups.h>

namespace cg = cooperative_groups;

#define TXN 256   // Tx
#define NA 256    // n_a
#define NF 128    // features
#define NS 512    // n_s
#define TYN 10
#define VOCAB 1024

// LDS layout constants for encoder (floats)
#define WS_STRIDE 388          // 64 gate-rows x 384 k, padded
#define AS_STRIDE 392          // 32 rows x 384 (h|x), padded
#define WS_FLOATS (64 * WS_STRIDE)                 // 24832
#define AS_FLOATS (32 * AS_STRIDE)                 // 12544
#define ENC_LDS_BYTES ((WS_FLOATS + AS_FLOATS + 64) * 4)   // 149,760 B

__device__ __forceinline__ float fsigmoid(float x) { return 1.f / (1.f + __expf(-x)); }
__device__ __forceinline__ float ftanh(float x)    { return 1.f - 2.f / (1.f + __expf(2.f * x)); }

// ---------------------------------------------------------------------------
// Persistent bidirectional LSTM encoder, weights resident in LDS.
// Grid: 256 blocks x 256 threads, cooperative launch (co-residency guarantee)
// but NO grid.sync: per-step sync is a 16-block barrier over the blocks
// sharing (dir, i-tile) — the only true data dependence (batch rows are
// independent across i-tiles). Producer: release fence (L2 writeback) +
// relaxed agent atomicAdd; consumer: spin on agent-scope load (no s_sleep),
// then stage h via agent-scope coherent loads (bypass stale L1/L2, keeps
// X/weight cache lines warm — no invalidating acquire fence).
// ---------------------------------------------------------------------------
__global__ __launch_bounds__(256, 1) void encoder_kernel(
    const float* __restrict__ X,
    const float* __restrict__ Wih_f, const float* __restrict__ Whh_f, const float* __restrict__ b_f,
    const float* __restrict__ Wih_b, const float* __restrict__ Whh_b, const float* __restrict__ b_b,
    float* __restrict__ a, unsigned int* __restrict__ bar)
{
    extern __shared__ float smem[];
    float* Wsh = smem;                       // [64][WS_STRIDE], k: 0..255 = Whh, 256..383 = Wih
    float* Ash = smem + WS_FLOATS;           // [32][AS_STRIDE], k: 0..255 = h, 256..383 = x
    float* bsh = smem + WS_FLOATS + AS_FLOATS;  // [64]

    const int tid = threadIdx.x;
    const int dir = blockIdx.x & 1;
    const int bid = blockIdx.x >> 1;   // 0..127
    const int i0 = (bid >> 4) * 32;    // 8 i-tiles
    const int j0 = (bid & 15) * 16;    // 16 j-tiles
    const int grp = dir * 8 + (bid >> 4);   // barrier group: 16 blocks share (dir, i-tile)
    unsigned int* gcnt = bar + grp * 32;    // 128B-padded counter

    const float* __restrict__ Wih = dir ? Wih_b : Wih_f;
    const float* __restrict__ Whh = dir ? Whh_b : Whh_f;
    const float* __restrict__ bv  = dir ? b_b  : b_f;

    const int jl = tid & 15;     // unit within j-tile
    const int ip = tid >> 4;     // 0..15
    const int iA = ip * 2;       // local batch row (even)

    // ---- one-time: weights + bias into LDS ----
    if (tid < 64) {
        int g = tid >> 4, j = tid & 15;
        bsh[tid] = bv[g * NA + j0 + j];
    }
    for (int r = 0; r < 64; ++r) {
        int row = (r >> 4) * NA + j0 + (r & 15);
        Wsh[r * WS_STRIDE + tid] = Whh[(size_t)row * NA + tid];
        if (tid < NF) Wsh[r * WS_STRIDE + 256 + tid] = Wih[(size_t)row * NF + tid];
    }

    float c0 = 0.f, c1 = 0.f;

    const float* W0 = Wsh + (size_t)jl * WS_STRIDE;            // gate i
    const float* W1 = W0 + 16 * WS_STRIDE;                     // gate f
    const float* W2 = W0 + 32 * WS_STRIDE;                     // gate g
    const float* W3 = W0 + 48 * WS_STRIDE;                     // gate o
    const float* A0 = Ash + (size_t)iA * AS_STRIDE;
    const float* A1 = A0 + AS_STRIDE;

    for (int step = 0; step < TXN; ++step) {
        const int t = dir ? (TXN - 1 - step) : step;

        // ---- stage A panel: h(prev) | x(t) ----
        if (step == 0) {
            #pragma unroll 4
            for (int r = 0; r < 32; ++r) Ash[r * AS_STRIDE + tid] = 0.f;
        } else {
            const int tprev = dir ? (t + 1) : (t - 1);
            #pragma unroll 8
            for (int r = 0; r < 32; ++r) {
                // coherent load: bypasses (possibly stale) L1/L2 on this XCD
                Ash[r * AS_STRIDE + tid] = __hip_atomic_load(
                    &a[(((size_t)(i0 + r) * TXN + tprev) << 9) + dir * NA + tid],
                    __ATOMIC_RELAXED, __HIP_MEMORY_SCOPE_AGENT);
            }
        }
        {
            const int kx = tid & 127;
            const int rbase = tid >> 7;   // 0..1
            #pragma unroll 4
            for (int rr = 0; rr < 16; ++rr) {
                int r = rr * 2 + rbase;
                Ash[r * AS_STRIDE + 256 + kx] = X[((size_t)(i0 + r) * TXN + t) * NF + kx];
            }
        }
        __syncthreads();

        float acc[2][4] = {{0.f,0.f,0.f,0.f},{0.f,0.f,0.f,0.f}};

        // depth-1 register-prefetch pipeline (1 wave/SIMD -> ILP must hide LDS latency)
        float4 na0 = *(const float4*)&A0[0];
        float4 na1 = *(const float4*)&A1[0];
        float4 nw0 = *(const float4*)&W0[0];
        float4 nw1 = *(const float4*)&W1[0];
        float4 nw2 = *(const float4*)&W2[0];
        float4 nw3 = *(const float4*)&W3[0];
        #pragma unroll 4
        for (int k4 = 0; k4 < 384; k4 += 4) {
            float4 ca0 = na0, ca1 = na1;
            float4 cw0 = nw0, cw1 = nw1, cw2 = nw2, cw3 = nw3;
            if (k4 + 4 < 384) {
                na0 = *(const float4*)&A0[k4 + 4];
                na1 = *(const float4*)&A1[k4 + 4];
                nw0 = *(const float4*)&W0[k4 + 4];
                nw1 = *(const float4*)&W1[k4 + 4];
                nw2 = *(const float4*)&W2[k4 + 4];
                nw3 = *(const float4*)&W3[k4 + 4];
            }
            acc[0][0] += ca0.x*cw0.x + ca0.y*cw0.y + ca0.z*cw0.z + ca0.w*cw0.w;
            acc[0][1] += ca0.x*cw1.x + ca0.y*cw1.y + ca0.z*cw1.z + ca0.w*cw1.w;
            acc[0][2] += ca0.x*cw2.x + ca0.y*cw2.y + ca0.z*cw2.z + ca0.w*cw2.w;
            acc[0][3] += ca0.x*cw3.x + ca0.y*cw3.y + ca0.z*cw3.z + ca0.w*cw3.w;
            acc[1][0] += ca1.x*cw0.x + ca1.y*cw0.y + ca1.z*cw0.z + ca1.w*cw0.w;
            acc[1][1] += ca1.x*cw1.x + ca1.y*cw1.y + ca1.z*cw1.z + ca1.w*cw1.w;
            acc[1][2] += ca1.x*cw2.x + ca1.y*cw2.y + ca1.z*cw2.z + ca1.w*cw2.w;
            acc[1][3] += ca1.x*cw3.x + ca1.y*cw3.y + ca1.z*cw3.z + ca1.w*cw3.w;
        }

        // gates, state update, write h into a
        float h0, h1;
        {
            float gi = fsigmoid(acc[0][0] + bsh[jl]);
            float gf = fsigmoid(acc[0][1] + bsh[16 + jl]);
            float gg = ftanh  (acc[0][2] + bsh[32 + jl]);
            float go = fsigmoid(acc[0][3] + bsh[48 + jl]);
            c0 = gf * c0 + gi * gg;
            h0 = go * ftanh(c0);
        }
        {
            float gi = fsigmoid(acc[1][0] + bsh[jl]);
            float gf = fsigmoid(acc[1][1] + bsh[16 + jl]);
            float gg = ftanh  (acc[1][2] + bsh[32 + jl]);
            float go = fsigmoid(acc[1][3] + bsh[48 + jl]);
            c1 = gf * c1 + gi * gg;
            h1 = go * ftanh(c1);
        }
        a[(((size_t)(i0 + iA)     * TXN + t) << 9) + dir * NA + j0 + jl] = h0;
        a[(((size_t)(i0 + iA + 1) * TXN + t) << 9) + dir * NA + j0 + jl] = h1;

        // ---- 16-block producer/consumer barrier (monotone counter) ----
        if (step != TXN - 1) {
            __syncthreads();   // all block stores reach L2 (vmcnt(0) before s_barrier)
            if (tid == 0) {
                __builtin_amdgcn_fence(__ATOMIC_RELEASE, "agent");  // L2 writeback
                __hip_atomic_fetch_add(gcnt, 1u, __ATOMIC_RELAXED, __HIP_MEMORY_SCOPE_AGENT);
                const unsigned int target = (unsigned int)(step + 1) * 16u;
                while (__hip_atomic_load(gcnt, __ATOMIC_RELAXED, __HIP_MEMORY_SCOPE_AGENT) < target) {}
            }
            __syncthreads();
        }
    }
}

// ---------------------------------------------------------------------------
// Generic tiled GEMM: C[M,N] = A[M,K] @ B[N,K]^T + bias[N]
// 64x64 tile, BK=16, 256 threads, 4x4 per thread. M must be multiple of 64,
// K multiple of 16. N masked.
// ---------------------------------------------------------------------------
__global__ __launch_bounds__(256) void gemm_bt(
    const float* __restrict__ A, int lda,
    const float* __restrict__ B, int ldb,
    const float* __restrict__ bias,
    float* __restrict__ C, int ldc,
    int N, int K)
{
    __shared__ float As[16][72];
    __shared__ float Bs[16][72];
    const int tid = threadIdx.x;
    const int i0 = blockIdx.x * 64;
    const int j0 = blockIdx.y * 64;
    const int tx = tid & 15, ty = tid >> 4;
    const int m  = tid >> 2;          // 0..63
    const int k4 = (tid & 3) * 4;

    float acc[4][4] = {};
    for (int kb = 0; kb < K; kb += 16) {
        float4 va = *(const float4*)&A[(size_t)(i0 + m) * lda + kb + k4];
        float4 vb;
        if (j0 + m < N) vb = *(const float4*)&B[(size_t)(j0 + m) * ldb + kb + k4];
        else            vb = make_float4(0.f, 0.f, 0.f, 0.f);
        __syncthreads();
        As[k4+0][m] = va.x; As[k4+1][m] = va.y; As[k4+2][m] = va.z; As[k4+3][m] = va.w;
        Bs[k4+0][m] = vb.x; Bs[k4+1][m] = vb.y; Bs[k4+2][m] = vb.z; Bs[k4+3][m] = vb.w;
        __syncthreads();
        #pragma unroll
        for (int k = 0; k < 16; ++k) {
            float4 a4 = *(const float4*)&As[k][ty * 4];
            float4 b4 = *(const float4*)&Bs[k][tx * 4];
            acc[0][0] += a4.x*b4.x; acc[0][1] += a4.x*b4.y; acc[0][2] += a4.x*b4.z; acc[0][3] += a4.x*b4.w;
            acc[1][0] += a4.y*b4.x; acc[1][1] += a4.y*b4.y; acc[1][2] += a4.y*b4.z; acc[1][3] += a4.y*b4.w;
            acc[2][0] += a4.z*b4.x; acc[2][1] += a4.z*b4.y; acc[2][2] += a4.z*b4.z; acc[2][3] += a4.z*b4.w;
            acc[3][0] += a4.w*b4.x; acc[3][1] += a4.w*b4.y; acc[3][2] += a4.w*b4.z; acc[3][3] += a4.w*b4.w;
        }
    }
    #pragma unroll
    for (int r = 0; r < 4; ++r) {
        int row = i0 + ty * 4 + r;
        #pragma unroll
        for (int c = 0; c < 4; ++c) {
            int col = j0 + tx * 4 + c;
            if (col < N) {
                float v = acc[r][c] + (bias ? bias[col] : 0.f);
                C[(size_t)row * ldc + col] = v;
            }
        }
    }
}

// ---------------------------------------------------------------------------
// Fused attention: block per batch row i.
// scores -> softmax over Tx -> context written into xcat[:, 0:512].
// ---------------------------------------------------------------------------
__global__ __launch_bounds__(256) void attn_kernel(
    const float* __restrict__ aW1,   // (m*Tx, 10), b1 already added
    const float* __restrict__ sW1,   // (m, 10)
    const float* __restrict__ W2,    // (10,)
    const float* __restrict__ b2,    // (1,)
    const float* __restrict__ a,     // (m, Tx, 512)
    float* __restrict__ xcat)        // (m, 1024)
{
    __shared__ float sh_s[10];
    __shared__ float sh_w2[10];
    __shared__ float red[256];
    __shared__ float al[256];
    const int i = blockIdx.x;
    const int tid = threadIdx.x;
    if (tid < 10) { sh_s[tid] = sW1[i * 10 + tid]; sh_w2[tid] = W2[tid]; }
    __syncthreads();

    float sum = b2[0];
    const float* ar = aW1 + ((size_t)i * TXN + tid) * 10;
    #pragma unroll
    for (int h = 0; h < 10; ++h) {
        float e = ftanh(ar[h] + sh_s[h]);
        sum += e * sh_w2[h];
    }
    float sc = fmaxf(sum, 0.f);

    red[tid] = sc;
    __syncthreads();
    for (int s = 128; s > 0; s >>= 1) {
        if (tid < s) red[tid] = fmaxf(red[tid], red[tid + s]);
        __syncthreads();
    }
    float mx = red[0];
    __syncthreads();
    float p = __expf(sc - mx);
    red[tid] = p;
    __syncthreads();
    for (int s = 128; s > 0; s >>= 1) {
        if (tid < s) red[tid] += red[tid + s];
        __syncthreads();
    }
    float inv = 1.f / red[0];
    al[tid] = p * inv;
    __syncthreads();

    float acc0 = 0.f, acc1 = 0.f;
    const float* arow = a + (size_t)i * TXN * NS;
    for (int t = 0; t < TXN; ++t) {
        float w = al[t];
        acc0 += w * arow[t * NS + tid];
        acc1 += w * arow[t * NS + 256 + tid];
    }
    xcat[(size_t)i * 1024 + tid]       = acc0;
    xcat[(size_t)i * 1024 + 256 + tid] = acc1;
}

// ---------------------------------------------------------------------------
// LSTM cell elementwise update from gate pre-activations.
// ---------------------------------------------------------------------------
__global__ __launch_bounds__(256) void cell_kernel(
    const float* __restrict__ g, float* __restrict__ c,
    float* __restrict__ s_buf, float* __restrict__ xcat)
{
    int idx = blockIdx.x * 256 + threadIdx.x;   // 256*512
    int i = idx >> 9, j = idx & 511;
    const float* gr = g + (size_t)i * 2048;
    float gi = fsigmoid(gr[j]);
    float gf = fsigmoid(gr[512 + j]);
    float gg = ftanh  (gr[1024 + j]);
    float go = fsigmoid(gr[1536 + j]);
    float cn = gf * c[idx] + gi * gg;
    c[idx] = cn;
    float h = go * ftanh(cn);
    s_buf[idx] = h;
    xcat[(size_t)i * 1024 + 512 + j] = h;
}

// Concatenate decoder LSTM weights: Wcat[r] = [Wc_ih[r] | Wc_hh[r]]
__global__ __launch_bounds__(256) void wcat_kernel(
    const float* __restrict__ Wc_ih, const float* __restrict__ Wc_hh,
    float* __restrict__ Wcat)
{
    int idx = blockIdx.x * 256 + threadIdx.x;   // 2048*1024
    int r = idx >> 10, k = idx & 1023;
    Wcat[idx] = (k < 512) ? Wc_ih[(size_t)r * 512 + k] : Wc_hh[(size_t)r * 512 + (k - 512)];
}

extern "C" void kernel_launch(void* const* d_in, const int* in_sizes, int n_in,
                              void* d_out, int out_size, void* d_ws, size_t ws_size,
                              hipStream_t stream)
{
    const float* X     = (const float*)d_in[0];
    const float* Wih_f = (const float*)d_in[1];
    const float* Whh_f = (const float*)d_in[2];
    const float* b_f   = (const float*)d_in[3];
    const float* Wih_b = (const float*)d_in[4];
    const float* Whh_b = (const float*)d_in[5];
    const float* b_b   = (const float*)d_in[6];
    const float* W1    = (const float*)d_in[7];
    const float* b1    = (const float*)d_in[8];
    const float* W2    = (const float*)d_in[9];
    const float* b2    = (const float*)d_in[10];
    const float* Wc_ih = (const float*)d_in[11];
    const float* Wc_hh = (const float*)d_in[12];
    const float* bc    = (const float*)d_in[13];
    const float* Wfc   = (const float*)d_in[14];
    const float* bfc   = (const float*)d_in[15];
    float* out = (float*)d_out;
    float* ws  = (float*)d_ws;

    // workspace layout (float offsets)
    float* c_buf = ws;                    // 256*512
    float* s_buf = ws + 131072;           // 256*512
    float* xcat  = ws + 262144;           // 256*1024  [ctx | s]
    float* a     = ws + 524288;           // 256*256*512
    float* aW1   = ws + 34078720;         // 65536*10
    float* Wcat  = ws + 34734080;         // 2048*1024
    float* sW1   = ws + 36831232;         // 256*10
    float* g_buf = ws + 36833792;         // 256*2048
    unsigned int* bar = (unsigned int*)(ws + 37358080);  // 16 groups x 32 uints (2KB)

    // allow >64KB dynamic LDS for the encoder (idempotent, host-side; capture-safe)
    static int lds_raised = 0;
    if (!lds_raised) {
        hipFuncSetAttribute(reinterpret_cast<const void*>(encoder_kernel),
                            hipFuncAttributeMaxDynamicSharedMemorySize, ENC_LDS_BYTES);
        lds_raised = 1;
    }

    // zero c, s, xcat (contiguous 2 MB) and barrier counters
    hipMemsetAsync(c_buf, 0, (size_t)524288 * sizeof(float), stream);
    hipMemsetAsync(bar, 0, 16 * 32 * sizeof(unsigned int), stream);

    wcat_kernel<<<8192, 256, 0, stream>>>(Wc_ih, Wc_hh, Wcat);

    // persistent bidirectional LSTM encoder (cooperative launch for
    // co-residency; sync is custom per-(dir,i-tile) 16-block barriers)
    {
        void* args[] = { (void*)&X, (void*)&Wih_f, (void*)&Whh_f, (void*)&b_f,
                         (void*)&Wih_b, (void*)&Whh_b, (void*)&b_b, (void*)&a, (void*)&bar };
        hipLaunchCooperativeKernel(reinterpret_cast<void*>(encoder_kernel),
                                   dim3(256), dim3(256), args, ENC_LDS_BYTES, stream);
    }

    // aW1 = a @ W1[:, :512]^T + b1   (loop-invariant across decoder steps)
    gemm_bt<<<dim3(1024, 1), 256, 0, stream>>>(a, 512, W1, 1024, b1, aW1, 10, 10, 512);

    for (int ty = 0; ty < TYN; ++ty) {
        // sW1 = s @ W1[:, 512:]^T
        gemm_bt<<<dim3(4, 1), 256, 0, stream>>>(s_buf, 512, W1 + 512, 1024, nullptr, sW1, 10, 10, 512);
        // attention + context -> xcat[:, :512]
        attn_kernel<<<256, 256, 0, stream>>>(aW1, sW1, W2, b2, a, xcat);
        // gates = xcat @ Wcat^T + bc
        gemm_bt<<<dim3(4, 32), 256, 0, stream>>>(xcat, 1024, Wcat, 1024, bc, g_buf, 2048, 2048, 1024);
        // cell update -> c, s (s also into xcat[:, 512:])
        cell_kernel<<<512, 256, 0, stream>>>(g_buf, c_buf, s_buf, xcat);
        // logits = s @ Wfc^T + bfc -> out[:, ty, :]
        gemm_bt<<<dim3(4, 16), 256, 0, stream>>>(s_buf, 512, Wfc, 512, bfc,
                                                 out + ty * VOCAB, TYN * VOCAB, VOCAB, 512);
    }
}

// Round 4
// 5428.372 us; speedup vs baseline: 3.7956x; 1.3501x over previous
//
#include <hip/hip_runtime.h>
#include <hip/hip_bf16.h>
#include <hip/hip_cooperative_groups.h>

namespace cg = cooperative_groups;

#define TXN 256   // Tx
#define NA 256    // n_a
#define NF 128    // features
#define NS 512    // n_s
#define TYN 10
#define VOCAB 1024

// ---- encoder LDS layout (split-bf16 planes) ----
#define A_STR 392   // bf16 elems/row: 384 + 8 pad (row = 784 B, 16B-aligned)
#define W_STR 392
#define WH_OFF 0                       // ushort index
#define WL_OFF (64 * W_STR)            // 25088
#define AH_OFF (2 * 64 * W_STR)        // 50176
#define AL_OFF (AH_OFF + 32 * A_STR)   // 62720
#define PRE_OFF_US (AL_OFF + 32 * A_STR)  // 75264 (ushort idx) -> byte 150528
#define ENC_LDS_BYTES (150528 + 32 * 68 * 4 + 64 * 4)   // 159,488 B

typedef __attribute__((ext_vector_type(8))) short bf16x8;
typedef __attribute__((ext_vector_type(4))) float f32x4;

__device__ __forceinline__ float fsigmoid(float x) { return 1.f / (1.f + __expf(-x)); }
__device__ __forceinline__ float ftanh(float x)    { return 1.f - 2.f / (1.f + __expf(2.f * x)); }

__device__ __forceinline__ void split_bf16(float v, unsigned short& hi, unsigned short& lo) {
    __hip_bfloat16 h = __float2bfloat16(v);
    float rem = v - __bfloat162float(h);
    __hip_bfloat16 l = __float2bfloat16(rem);
    hi = *reinterpret_cast<unsigned short*>(&h);
    lo = *reinterpret_cast<unsigned short*>(&l);
}

// ---------------------------------------------------------------------------
// Persistent bidirectional LSTM encoder — MFMA (split-bf16) version.
// 256 blocks x 256 threads, cooperative launch; per-(dir,i-tile) 16-block
// barrier (R3 structure). Per block: C[32 rows][64 gate-rows] += A[32][384]
// x W^T via mfma_f32_16x16x32_bf16 with 3-product hi/lo split (~fp32 prec).
// Weights resident in LDS as bf16 hi/lo planes; A-panel re-staged per step.
// Gate combine via LDS preact scratch back to per-thread (2row x 1unit)
// mapping; c-state in registers for all 256 steps.
// ---------------------------------------------------------------------------
__global__ __launch_bounds__(256, 1) void encoder_kernel(
    const float* __restrict__ X,
    const float* __restrict__ Wih_f, const float* __restrict__ Whh_f, const float* __restrict__ b_f,
    const float* __restrict__ Wih_b, const float* __restrict__ Whh_b, const float* __restrict__ b_b,
    float* __restrict__ a, unsigned int* __restrict__ bar)
{
    extern __shared__ unsigned char smem_raw[];
    unsigned short* Wh  = (unsigned short*)smem_raw;
    unsigned short* Wl  = Wh + WL_OFF - WH_OFF;      // == (ushort*)smem_raw + WL_OFF
    unsigned short* Ahh = (unsigned short*)smem_raw + AH_OFF;
    unsigned short* All = (unsigned short*)smem_raw + AL_OFF;
    float* Pre = (float*)(smem_raw + (size_t)PRE_OFF_US * 2);   // [32][68]
    float* bsh = Pre + 32 * 68;                                  // [64]

    const int tid = threadIdx.x;
    const int dir = blockIdx.x & 1;
    const int bid = blockIdx.x >> 1;   // 0..127
    const int i0 = (bid >> 4) * 32;    // 8 i-tiles
    const int j0 = (bid & 15) * 16;    // 16 j-tiles
    const int grp = dir * 8 + (bid >> 4);
    unsigned int* gcnt = bar + grp * 32;

    const float* __restrict__ Wih = dir ? Wih_b : Wih_f;
    const float* __restrict__ Whh = dir ? Whh_b : Whh_f;
    const float* __restrict__ bv  = dir ? b_b  : b_f;

    const int jl = tid & 15;     // unit within j-tile (elementwise phase)
    const int ip = tid >> 4;     // 0..15
    const int iA = ip * 2;       // local batch row (even)

    // ---- one-time: weights (split to bf16 hi/lo) + bias into LDS ----
    if (tid < 64) bsh[tid] = bv[(tid >> 4) * NA + j0 + (tid & 15)];
    for (int r = 0; r < 64; ++r) {
        int row = (r >> 4) * NA + j0 + (r & 15);
        unsigned short hi, lo;
        split_bf16(Whh[(size_t)row * NA + tid], hi, lo);
        Wh[r * W_STR + tid] = hi;
        Wl[r * W_STR + tid] = lo;
        if (tid < NF) {
            split_bf16(Wih[(size_t)row * NF + tid], hi, lo);
            Wh[r * W_STR + 256 + tid] = hi;
            Wl[r * W_STR + 256 + tid] = lo;
        }
    }

    float c0 = 0.f, c1 = 0.f;

    // MFMA wave assignment: wave wv -> row-tile (wv>>1), gate pair (wv&1)*2
    const int lane = tid & 63;
    const int wv   = tid >> 6;
    const int rt   = wv >> 1;
    const int g0   = (wv & 1) * 2;
    const int ln   = lane & 15;
    const int quad = lane >> 4;
    const unsigned short* pAh = Ahh + (rt * 16 + ln) * A_STR + quad * 8;
    const unsigned short* pAl = All + (rt * 16 + ln) * A_STR + quad * 8;
    const unsigned short* pW0h = Wh + (g0 * 16 + ln) * W_STR + quad * 8;
    const unsigned short* pW0l = Wl + (g0 * 16 + ln) * W_STR + quad * 8;
    const unsigned short* pW1h = pW0h + 16 * W_STR;
    const unsigned short* pW1l = pW0l + 16 * W_STR;

    for (int step = 0; step < TXN; ++step) {
        const int t = dir ? (TXN - 1 - step) : step;

        // ---- stage A panel (hi/lo bf16): h(prev) | x(t) ----
        if (step == 0) {
            #pragma unroll 4
            for (int r = 0; r < 32; ++r) {
                Ahh[r * A_STR + tid] = 0;
                All[r * A_STR + tid] = 0;
            }
        } else {
            const int tprev = dir ? (t + 1) : (t - 1);
            #pragma unroll 8
            for (int r = 0; r < 32; ++r) {
                float v = __hip_atomic_load(
                    &a[(((size_t)(i0 + r) * TXN + tprev) << 9) + dir * NA + tid],
                    __ATOMIC_RELAXED, __HIP_MEMORY_SCOPE_AGENT);
                unsigned short hi, lo;
                split_bf16(v, hi, lo);
                Ahh[r * A_STR + tid] = hi;
                All[r * A_STR + tid] = lo;
            }
        }
        {
            const int kx = tid & 127;
            const int rbase = tid >> 7;   // 0..1
            #pragma unroll 4
            for (int rr = 0; rr < 16; ++rr) {
                int r = rr * 2 + rbase;
                float v = X[((size_t)(i0 + r) * TXN + t) * NF + kx];
                unsigned short hi, lo;
                split_bf16(v, hi, lo);
                Ahh[r * A_STR + 256 + kx] = hi;
                All[r * A_STR + 256 + kx] = lo;
            }
        }
        __syncthreads();

        // ---- MFMA phase: 2 C-tiles per wave, K = 12 chunks of 32 ----
        f32x4 acc0 = {0.f, 0.f, 0.f, 0.f};
        f32x4 acc1 = {0.f, 0.f, 0.f, 0.f};
        #pragma unroll
        for (int kc = 0; kc < 12; ++kc) {
            bf16x8 fah = *(const bf16x8*)(pAh + kc * 32);
            bf16x8 fal = *(const bf16x8*)(pAl + kc * 32);
            bf16x8 w0h = *(const bf16x8*)(pW0h + kc * 32);
            bf16x8 w0l = *(const bf16x8*)(pW0l + kc * 32);
            bf16x8 w1h = *(const bf16x8*)(pW1h + kc * 32);
            bf16x8 w1l = *(const bf16x8*)(pW1l + kc * 32);
            acc0 = __builtin_amdgcn_mfma_f32_16x16x32_bf16(fal, w0h, acc0, 0, 0, 0);
            acc0 = __builtin_amdgcn_mfma_f32_16x16x32_bf16(fah, w0l, acc0, 0, 0, 0);
            acc0 = __builtin_amdgcn_mfma_f32_16x16x32_bf16(fah, w0h, acc0, 0, 0, 0);
            acc1 = __builtin_amdgcn_mfma_f32_16x16x32_bf16(fal, w1h, acc1, 0, 0, 0);
            acc1 = __builtin_amdgcn_mfma_f32_16x16x32_bf16(fah, w1l, acc1, 0, 0, 0);
            acc1 = __builtin_amdgcn_mfma_f32_16x16x32_bf16(fah, w1h, acc1, 0, 0, 0);
        }
        // C/D layout: col = lane&15 (gate-row within tile), row = quad*4+reg
        #pragma unroll
        for (int reg = 0; reg < 4; ++reg) {
            int prow = rt * 16 + quad * 4 + reg;
            Pre[prow * 68 + g0 * 16 + ln]       = acc0[reg];
            Pre[prow * 68 + (g0 + 1) * 16 + ln] = acc1[reg];
        }
        __syncthreads();

        // ---- elementwise phase: per-thread (2 rows x 1 unit), c in regs ----
        float h0, h1;
        {
            float gi = fsigmoid(Pre[iA * 68 +      jl] + bsh[jl]);
            float gf = fsigmoid(Pre[iA * 68 + 16 + jl] + bsh[16 + jl]);
            float gg = ftanh  (Pre[iA * 68 + 32 + jl] + bsh[32 + jl]);
            float go = fsigmoid(Pre[iA * 68 + 48 + jl] + bsh[48 + jl]);
            c0 = gf * c0 + gi * gg;
            h0 = go * ftanh(c0);
        }
        {
            float gi = fsigmoid(Pre[(iA + 1) * 68 +      jl] + bsh[jl]);
            float gf = fsigmoid(Pre[(iA + 1) * 68 + 16 + jl] + bsh[16 + jl]);
            float gg = ftanh  (Pre[(iA + 1) * 68 + 32 + jl] + bsh[32 + jl]);
            float go = fsigmoid(Pre[(iA + 1) * 68 + 48 + jl] + bsh[48 + jl]);
            c1 = gf * c1 + gi * gg;
            h1 = go * ftanh(c1);
        }
        a[(((size_t)(i0 + iA)     * TXN + t) << 9) + dir * NA + j0 + jl] = h0;
        a[(((size_t)(i0 + iA + 1) * TXN + t) << 9) + dir * NA + j0 + jl] = h1;

        // ---- 16-block producer/consumer barrier (R3 structure) ----
        if (step != TXN - 1) {
            __syncthreads();
            if (tid == 0) {
                __builtin_amdgcn_fence(__ATOMIC_RELEASE, "agent");
                __hip_atomic_fetch_add(gcnt, 1u, __ATOMIC_RELAXED, __HIP_MEMORY_SCOPE_AGENT);
                const unsigned int target = (unsigned int)(step + 1) * 16u;
                while (__hip_atomic_load(gcnt, __ATOMIC_RELAXED, __HIP_MEMORY_SCOPE_AGENT) < target) {}
            }
            __syncthreads();
        }
    }
}

// ---------------------------------------------------------------------------
// Tall-skinny: aW1[m*Tx][10] = a[m*Tx][512] @ W1[:, :512]^T + b1
// Block = 64 rows, thread = (row, k-quarter). W1 slice in LDS (broadcast).
// ---------------------------------------------------------------------------
__global__ __launch_bounds__(256) void attn_prep(
    const float* __restrict__ a, const float* __restrict__ W1,
    const float* __restrict__ b1, float* __restrict__ aW1)
{
    __shared__ float Wsh[10][516];
    __shared__ float red[64][10][4];
    const int tid = threadIdx.x;
    for (int idx = tid; idx < 10 * 512; idx += 256) {
        int o = idx >> 9, k = idx & 511;
        Wsh[o][k] = W1[o * 1024 + k];
    }
    __syncthreads();
    const int r = tid >> 2, kq = tid & 3;
    const float* ar = a + ((size_t)blockIdx.x * 64 + r) * 512 + kq * 128;
    float acc[10] = {};
    for (int k = 0; k < 128; k += 4) {
        float4 v = *(const float4*)&ar[k];
        #pragma unroll
        for (int o = 0; o < 10; ++o) {
            float4 w = *(const float4*)&Wsh[o][kq * 128 + k];
            acc[o] += v.x * w.x + v.y * w.y + v.z * w.z + v.w * w.w;
        }
    }
    #pragma unroll
    for (int o = 0; o < 10; ++o) red[r][o][kq] = acc[o];
    __syncthreads();
    for (int idx = tid; idx < 640; idx += 256) {
        int rr = idx / 10, o = idx % 10;
        float s = red[rr][o][0] + red[rr][o][1] + red[rr][o][2] + red[rr][o][3] + b1[o];
        aW1[((size_t)blockIdx.x * 64 + rr) * 10 + o] = s;
    }
}

// ---------------------------------------------------------------------------
// Generic tiled GEMM: C[M,N] = A[M,K] @ B[N,K]^T + bias[N]
// 64x64 tile, BK=16, 256 threads, 4x4 per thread.
// ---------------------------------------------------------------------------
__global__ __launch_bounds__(256) void gemm_bt(
    const float* __restrict__ A, int lda,
    const float* __restrict__ B, int ldb,
    const float* __restrict__ bias,
    float* __restrict__ C, int ldc,
    int N, int K)
{
    __shared__ float As[16][72];
    __shared__ float Bs[16][72];
    const int tid = threadIdx.x;
    const int i0 = blockIdx.x * 64;
    const int j0 = blockIdx.y * 64;
    const int tx = tid & 15, ty = tid >> 4;
    const int m  = tid >> 2;
    const int k4 = (tid & 3) * 4;

    float acc[4][4] = {};
    for (int kb = 0; kb < K; kb += 16) {
        float4 va = *(const float4*)&A[(size_t)(i0 + m) * lda + kb + k4];
        float4 vb;
        if (j0 + m < N) vb = *(const float4*)&B[(size_t)(j0 + m) * ldb + kb + k4];
        else            vb = make_float4(0.f, 0.f, 0.f, 0.f);
        __syncthreads();
        As[k4+0][m] = va.x; As[k4+1][m] = va.y; As[k4+2][m] = va.z; As[k4+3][m] = va.w;
        Bs[k4+0][m] = vb.x; Bs[k4+1][m] = vb.y; Bs[k4+2][m] = vb.z; Bs[k4+3][m] = vb.w;
        __syncthreads();
        #pragma unroll
        for (int k = 0; k < 16; ++k) {
            float4 a4 = *(const float4*)&As[k][ty * 4];
            float4 b4 = *(const float4*)&Bs[k][tx * 4];
            acc[0][0] += a4.x*b4.x; acc[0][1] += a4.x*b4.y; acc[0][2] += a4.x*b4.z; acc[0][3] += a4.x*b4.w;
            acc[1][0] += a4.y*b4.x; acc[1][1] += a4.y*b4.y; acc[1][2] += a4.y*b4.z; acc[1][3] += a4.y*b4.w;
            acc[2][0] += a4.z*b4.x; acc[2][1] += a4.z*b4.y; acc[2][2] += a4.z*b4.z; acc[2][3] += a4.z*b4.w;
            acc[3][0] += a4.w*b4.x; acc[3][1] += a4.w*b4.y; acc[3][2] += a4.w*b4.z; acc[3][3] += a4.w*b4.w;
        }
    }
    #pragma unroll
    for (int r = 0; r < 4; ++r) {
        int row = i0 + ty * 4 + r;
        #pragma unroll
        for (int c = 0; c < 4; ++c) {
            int col = j0 + tx * 4 + c;
            if (col < N) {
                float v = acc[r][c] + (bias ? bias[col] : 0.f);
                C[(size_t)row * ldc + col] = v;
            }
        }
    }
}

// ---------------------------------------------------------------------------
// Fused attention: block per batch row i.
// ---------------------------------------------------------------------------
__global__ __launch_bounds__(256) void attn_kernel(
    const float* __restrict__ aW1,   // (m*Tx, 10), b1 already added
    const float* __restrict__ sW1,   // (m, 10)
    const float* __restrict__ W2,    // (10,)
    const float* __restrict__ b2,    // (1,)
    const float* __restrict__ a,     // (m, Tx, 512)
    float* __restrict__ xcat)        // (m, 1024)
{
    __shared__ float sh_s[10];
    __shared__ float sh_w2[10];
    __shared__ float red[256];
    __shared__ float al[256];
    const int i = blockIdx.x;
    const int tid = threadIdx.x;
    if (tid < 10) { sh_s[tid] = sW1[i * 10 + tid]; sh_w2[tid] = W2[tid]; }
    __syncthreads();

    float sum = b2[0];
    const float* ar = aW1 + ((size_t)i * TXN + tid) * 10;
    #pragma unroll
    for (int h = 0; h < 10; ++h) {
        float e = ftanh(ar[h] + sh_s[h]);
        sum += e * sh_w2[h];
    }
    float sc = fmaxf(sum, 0.f);

    red[tid] = sc;
    __syncthreads();
    for (int s = 128; s > 0; s >>= 1) {
        if (tid < s) red[tid] = fmaxf(red[tid], red[tid + s]);
        __syncthreads();
    }
    float mx = red[0];
    __syncthreads();
    float p = __expf(sc - mx);
    red[tid] = p;
    __syncthreads();
    for (int s = 128; s > 0; s >>= 1) {
        if (tid < s) red[tid] += red[tid + s];
        __syncthreads();
    }
    float inv = 1.f / red[0];
    al[tid] = p * inv;
    __syncthreads();

    float acc0 = 0.f, acc1 = 0.f;
    const float* arow = a + (size_t)i * TXN * NS;
    for (int t = 0; t < TXN; ++t) {
        float w = al[t];
        acc0 += w * arow[t * NS + tid];
        acc1 += w * arow[t * NS + 256 + tid];
    }
    xcat[(size_t)i * 1024 + tid]       = acc0;
    xcat[(size_t)i * 1024 + 256 + tid] = acc1;
}

// ---------------------------------------------------------------------------
// LSTM cell elementwise update from gate pre-activations.
// ---------------------------------------------------------------------------
__global__ __launch_bounds__(256) void cell_kernel(
    const float* __restrict__ g, float* __restrict__ c,
    float* __restrict__ s_buf, float* __restrict__ xcat)
{
    int idx = blockIdx.x * 256 + threadIdx.x;   // 256*512
    int i = idx >> 9, j = idx & 511;
    const float* gr = g + (size_t)i * 2048;
    float gi = fsigmoid(gr[j]);
    float gf = fsigmoid(gr[512 + j]);
    float gg = ftanh  (gr[1024 + j]);
    float go = fsigmoid(gr[1536 + j]);
    float cn = gf * c[idx] + gi * gg;
    c[idx] = cn;
    float h = go * ftanh(cn);
    s_buf[idx] = h;
    xcat[(size_t)i * 1024 + 512 + j] = h;
}

// Concatenate decoder LSTM weights: Wcat[r] = [Wc_ih[r] | Wc_hh[r]]
__global__ __launch_bounds__(256) void wcat_kernel(
    const float* __restrict__ Wc_ih, const float* __restrict__ Wc_hh,
    float* __restrict__ Wcat)
{
    int idx = blockIdx.x * 256 + threadIdx.x;   // 2048*1024
    int r = idx >> 10, k = idx & 1023;
    Wcat[idx] = (k < 512) ? Wc_ih[(size_t)r * 512 + k] : Wc_hh[(size_t)r * 512 + (k - 512)];
}

extern "C" void kernel_launch(void* const* d_in, const int* in_sizes, int n_in,
                              void* d_out, int out_size, void* d_ws, size_t ws_size,
                              hipStream_t stream)
{
    const float* X     = (const float*)d_in[0];
    const float* Wih_f = (const float*)d_in[1];
    const float* Whh_f = (const float*)d_in[2];
    const float* b_f   = (const float*)d_in[3];
    const float* Wih_b = (const float*)d_in[4];
    const float* Whh_b = (const float*)d_in[5];
    const float* b_b   = (const float*)d_in[6];
    const float* W1    = (const float*)d_in[7];
    const float* b1    = (const float*)d_in[8];
    const float* W2    = (const float*)d_in[9];
    const float* b2    = (const float*)d_in[10];
    const float* Wc_ih = (const float*)d_in[11];
    const float* Wc_hh = (const float*)d_in[12];
    const float* bc    = (const float*)d_in[13];
    const float* Wfc   = (const float*)d_in[14];
    const float* bfc   = (const float*)d_in[15];
    float* out = (float*)d_out;
    float* ws  = (float*)d_ws;

    // workspace layout (float offsets)
    float* c_buf = ws;                    // 256*512
    float* s_buf = ws + 131072;           // 256*512
    float* xcat  = ws + 262144;           // 256*1024  [ctx | s]
    float* a     = ws + 524288;           // 256*256*512
    float* aW1   = ws + 34078720;         // 65536*10
    float* Wcat  = ws + 34734080;         // 2048*1024
    float* sW1   = ws + 36831232;         // 256*10
    float* g_buf = ws + 36833792;         // 256*2048
    unsigned int* bar = (unsigned int*)(ws + 37358080);  // 16 groups x 32 uints

    static int lds_raised = 0;
    if (!lds_raised) {
        hipFuncSetAttribute(reinterpret_cast<const void*>(encoder_kernel),
                            hipFuncAttributeMaxDynamicSharedMemorySize, ENC_LDS_BYTES);
        lds_raised = 1;
    }

    // zero c, s, xcat (contiguous 2 MB) and barrier counters
    hipMemsetAsync(c_buf, 0, (size_t)524288 * sizeof(float), stream);
    hipMemsetAsync(bar, 0, 16 * 32 * sizeof(unsigned int), stream);

    wcat_kernel<<<8192, 256, 0, stream>>>(Wc_ih, Wc_hh, Wcat);

    // persistent bidirectional LSTM encoder
    {
        void* args[] = { (void*)&X, (void*)&Wih_f, (void*)&Whh_f, (void*)&b_f,
                         (void*)&Wih_b, (void*)&Whh_b, (void*)&b_b, (void*)&a, (void*)&bar };
        hipLaunchCooperativeKernel(reinterpret_cast<void*>(encoder_kernel),
                                   dim3(256), dim3(256), args, ENC_LDS_BYTES, stream);
    }

    // aW1 = a @ W1[:, :512]^T + b1   (loop-invariant across decoder steps)
    attn_prep<<<1024, 256, 0, stream>>>(a, W1, b1, aW1);

    for (int ty = 0; ty < TYN; ++ty) {
        // sW1 = s @ W1[:, 512:]^T
        gemm_bt<<<dim3(4, 1), 256, 0, stream>>>(s_buf, 512, W1 + 512, 1024, nullptr, sW1, 10, 10, 512);
        // attention + context -> xcat[:, :512]
        attn_kernel<<<256, 256, 0, stream>>>(aW1, sW1, W2, b2, a, xcat);
        // gates = xcat @ Wcat^T + bc
        gemm_bt<<<dim3(4, 32), 256, 0, stream>>>(xcat, 1024, Wcat, 1024, bc, g_buf, 2048, 2048, 1024);
        // cell update -> c, s (s also into xcat[:, 512:])
        cell_kernel<<<512, 256, 0, stream>>>(g_buf, c_buf, s_buf, xcat);
        // logits = s @ Wfc^T + bfc -> out[:, ty, :]
        gemm_bt<<<dim3(4, 16), 256, 0, stream>>>(s_buf, 512, Wfc, 512, bfc,
                                                 out + ty * VOCAB, TYN * VOCAB, VOCAB, 512);
    }
}

// Round 5
// 4326.858 us; speedup vs baseline: 4.7619x; 1.2546x over previous
//
#include <hip/hip_runtime.h>
#include <hip/hip_bf16.h>
#include <hip/hip_cooperative_groups.h>

namespace cg = cooperative_groups;

#define TXN 256   // Tx
#define NA 256    // n_a
#define NF 128    // features
#define NS 512    // n_s
#define TYN 10
#define VOCAB 1024

// ---- encoder LDS layout (split-bf16 planes) ----
#define A_STR 392   // bf16 elems/row: 384 + 8 pad (row = 784 B, 16B-aligned)
#define W_STR 392
#define WH_OFF 0                       // ushort index
#define WL_OFF (64 * W_STR)            // 25088
#define AH_OFF (2 * 64 * W_STR)        // 50176
#define AL_OFF (AH_OFF + 32 * A_STR)   // 62720
#define PRE_OFF_US (AL_OFF + 32 * A_STR)  // 75264 (ushort idx) -> byte 150528
#define ENC_LDS_BYTES (150528 + 32 * 68 * 4 + 64 * 4)   // 159,488 B

typedef __attribute__((ext_vector_type(8))) short bf16x8;
typedef __attribute__((ext_vector_type(4))) float f32x4;

__device__ __forceinline__ float fsigmoid(float x) { return 1.f / (1.f + __expf(-x)); }
__device__ __forceinline__ float ftanh(float x)    { return 1.f - 2.f / (1.f + __expf(2.f * x)); }

__device__ __forceinline__ void split_bf16(float v, unsigned short& hi, unsigned short& lo) {
    __hip_bfloat16 h = __float2bfloat16(v);
    float rem = v - __bfloat162float(h);
    __hip_bfloat16 l = __float2bfloat16(rem);
    hi = *reinterpret_cast<unsigned short*>(&h);
    lo = *reinterpret_cast<unsigned short*>(&l);
}

// ---------------------------------------------------------------------------
// Persistent bidirectional LSTM encoder — MFMA (split-bf16) version.
// 256 blocks x 256 threads, cooperative launch; per-(dir,i-tile) 16-block
// barrier. h is exchanged via WRITE-THROUGH agent-scope atomic stores
// (sc-bit path to the device coherence point) — no release fence, hence no
// per-step buffer_wbl2 L2-writeback walk (the R4 ~10us/step stall).
// Ordering: __syncthreads() drains vmcnt(0) in every wave before s_barrier,
// so all h stores are at the coherence point before tid0's flag atomicAdd.
// ---------------------------------------------------------------------------
__global__ __launch_bounds__(256, 1) void encoder_kernel(
    const float* __restrict__ X,
    const float* __restrict__ Wih_f, const float* __restrict__ Whh_f, const float* __restrict__ b_f,
    const float* __restrict__ Wih_b, const float* __restrict__ Whh_b, const float* __restrict__ b_b,
    float* __restrict__ a, unsigned int* __restrict__ bar)
{
    extern __shared__ unsigned char smem_raw[];
    unsigned short* Wh  = (unsigned short*)smem_raw;
    unsigned short* Wl  = Wh + WL_OFF - WH_OFF;
    unsigned short* Ahh = (unsigned short*)smem_raw + AH_OFF;
    unsigned short* All = (unsigned short*)smem_raw + AL_OFF;
    float* Pre = (float*)(smem_raw + (size_t)PRE_OFF_US * 2);   // [32][68]
    float* bsh = Pre + 32 * 68;                                  // [64]

    const int tid = threadIdx.x;
    const int dir = blockIdx.x & 1;
    const int bid = blockIdx.x >> 1;   // 0..127
    const int i0 = (bid >> 4) * 32;    // 8 i-tiles
    const int j0 = (bid & 15) * 16;    // 16 j-tiles
    const int grp = dir * 8 + (bid >> 4);
    unsigned int* gcnt = bar + grp * 32;

    const float* __restrict__ Wih = dir ? Wih_b : Wih_f;
    const float* __restrict__ Whh = dir ? Whh_b : Whh_f;
    const float* __restrict__ bv  = dir ? b_b  : b_f;

    const int jl = tid & 15;     // unit within j-tile (elementwise phase)
    const int ip = tid >> 4;     // 0..15
    const int iA = ip * 2;       // local batch row (even)

    // ---- one-time: weights (split to bf16 hi/lo) + bias into LDS ----
    if (tid < 64) bsh[tid] = bv[(tid >> 4) * NA + j0 + (tid & 15)];
    for (int r = 0; r < 64; ++r) {
        int row = (r >> 4) * NA + j0 + (r & 15);
        unsigned short hi, lo;
        split_bf16(Whh[(size_t)row * NA + tid], hi, lo);
        Wh[r * W_STR + tid] = hi;
        Wl[r * W_STR + tid] = lo;
        if (tid < NF) {
            split_bf16(Wih[(size_t)row * NF + tid], hi, lo);
            Wh[r * W_STR + 256 + tid] = hi;
            Wl[r * W_STR + 256 + tid] = lo;
        }
    }

    float c0 = 0.f, c1 = 0.f;

    // MFMA wave assignment: wave wv -> row-tile (wv>>1), gate pair (wv&1)*2
    const int lane = tid & 63;
    const int wv   = tid >> 6;
    const int rt   = wv >> 1;
    const int g0   = (wv & 1) * 2;
    const int ln   = lane & 15;
    const int quad = lane >> 4;
    const unsigned short* pAh = Ahh + (rt * 16 + ln) * A_STR + quad * 8;
    const unsigned short* pAl = All + (rt * 16 + ln) * A_STR + quad * 8;
    const unsigned short* pW0h = Wh + (g0 * 16 + ln) * W_STR + quad * 8;
    const unsigned short* pW0l = Wl + (g0 * 16 + ln) * W_STR + quad * 8;
    const unsigned short* pW1h = pW0h + 16 * W_STR;
    const unsigned short* pW1l = pW0l + 16 * W_STR;

    for (int step = 0; step < TXN; ++step) {
        const int t = dir ? (TXN - 1 - step) : step;

        // ---- stage A panel (hi/lo bf16): h(prev) | x(t) ----
        if (step == 0) {
            #pragma unroll 4
            for (int r = 0; r < 32; ++r) {
                Ahh[r * A_STR + tid] = 0;
                All[r * A_STR + tid] = 0;
            }
        } else {
            const int tprev = dir ? (t + 1) : (t - 1);
            #pragma unroll 8
            for (int r = 0; r < 32; ++r) {
                float v = __hip_atomic_load(
                    &a[(((size_t)(i0 + r) * TXN + tprev) << 9) + dir * NA + tid],
                    __ATOMIC_RELAXED, __HIP_MEMORY_SCOPE_AGENT);
                unsigned short hi, lo;
                split_bf16(v, hi, lo);
                Ahh[r * A_STR + tid] = hi;
                All[r * A_STR + tid] = lo;
            }
        }
        {
            const int kx = tid & 127;
            const int rbase = tid >> 7;   // 0..1
            #pragma unroll 4
            for (int rr = 0; rr < 16; ++rr) {
                int r = rr * 2 + rbase;
                float v = X[((size_t)(i0 + r) * TXN + t) * NF + kx];
                unsigned short hi, lo;
                split_bf16(v, hi, lo);
                Ahh[r * A_STR + 256 + kx] = hi;
                All[r * A_STR + 256 + kx] = lo;
            }
        }
        __syncthreads();

        // ---- MFMA phase: 2 C-tiles per wave, K = 12 chunks of 32 ----
        f32x4 acc0 = {0.f, 0.f, 0.f, 0.f};
        f32x4 acc1 = {0.f, 0.f, 0.f, 0.f};
        #pragma unroll
        for (int kc = 0; kc < 12; ++kc) {
            bf16x8 fah = *(const bf16x8*)(pAh + kc * 32);
            bf16x8 fal = *(const bf16x8*)(pAl + kc * 32);
            bf16x8 w0h = *(const bf16x8*)(pW0h + kc * 32);
            bf16x8 w0l = *(const bf16x8*)(pW0l + kc * 32);
            bf16x8 w1h = *(const bf16x8*)(pW1h + kc * 32);
            bf16x8 w1l = *(const bf16x8*)(pW1l + kc * 32);
            acc0 = __builtin_amdgcn_mfma_f32_16x16x32_bf16(fal, w0h, acc0, 0, 0, 0);
            acc0 = __builtin_amdgcn_mfma_f32_16x16x32_bf16(fah, w0l, acc0, 0, 0, 0);
            acc0 = __builtin_amdgcn_mfma_f32_16x16x32_bf16(fah, w0h, acc0, 0, 0, 0);
            acc1 = __builtin_amdgcn_mfma_f32_16x16x32_bf16(fal, w1h, acc1, 0, 0, 0);
            acc1 = __builtin_amdgcn_mfma_f32_16x16x32_bf16(fah, w1l, acc1, 0, 0, 0);
            acc1 = __builtin_amdgcn_mfma_f32_16x16x32_bf16(fah, w1h, acc1, 0, 0, 0);
        }
        // C/D layout: col = lane&15 (gate-row within tile), row = quad*4+reg
        #pragma unroll
        for (int reg = 0; reg < 4; ++reg) {
            int prow = rt * 16 + quad * 4 + reg;
            Pre[prow * 68 + g0 * 16 + ln]       = acc0[reg];
            Pre[prow * 68 + (g0 + 1) * 16 + ln] = acc1[reg];
        }
        __syncthreads();

        // ---- elementwise phase: per-thread (2 rows x 1 unit), c in regs ----
        float h0, h1;
        {
            float gi = fsigmoid(Pre[iA * 68 +      jl] + bsh[jl]);
            float gf = fsigmoid(Pre[iA * 68 + 16 + jl] + bsh[16 + jl]);
            float gg = ftanh  (Pre[iA * 68 + 32 + jl] + bsh[32 + jl]);
            float go = fsigmoid(Pre[iA * 68 + 48 + jl] + bsh[48 + jl]);
            c0 = gf * c0 + gi * gg;
            h0 = go * ftanh(c0);
        }
        {
            float gi = fsigmoid(Pre[(iA + 1) * 68 +      jl] + bsh[jl]);
            float gf = fsigmoid(Pre[(iA + 1) * 68 + 16 + jl] + bsh[16 + jl]);
            float gg = ftanh  (Pre[(iA + 1) * 68 + 32 + jl] + bsh[32 + jl]);
            float go = fsigmoid(Pre[(iA + 1) * 68 + 48 + jl] + bsh[48 + jl]);
            c1 = gf * c1 + gi * gg;
            h1 = go * ftanh(c1);
        }
        // write-through (agent-scope) h stores: visible at coherence point
        // once this wave's vmcnt drains (which __syncthreads below forces).
        __hip_atomic_store(
            &a[(((size_t)(i0 + iA)     * TXN + t) << 9) + dir * NA + j0 + jl],
            h0, __ATOMIC_RELAXED, __HIP_MEMORY_SCOPE_AGENT);
        __hip_atomic_store(
            &a[(((size_t)(i0 + iA + 1) * TXN + t) << 9) + dir * NA + j0 + jl],
            h1, __ATOMIC_RELAXED, __HIP_MEMORY_SCOPE_AGENT);

        // ---- 16-block producer/consumer barrier (no wbl2 fence) ----
        if (step != TXN - 1) {
            __syncthreads();   // drains vmcnt(0) per wave before s_barrier
            if (tid == 0) {
                __hip_atomic_fetch_add(gcnt, 1u, __ATOMIC_RELAXED, __HIP_MEMORY_SCOPE_AGENT);
                const unsigned int target = (unsigned int)(step + 1) * 16u;
                while (__hip_atomic_load(gcnt, __ATOMIC_RELAXED, __HIP_MEMORY_SCOPE_AGENT) < target) {}
            }
            __syncthreads();
        }
    }
}

// ---------------------------------------------------------------------------
// Tall-skinny: aW1[m*Tx][10] = a[m*Tx][512] @ W1[:, :512]^T + b1
// ---------------------------------------------------------------------------
__global__ __launch_bounds__(256) void attn_prep(
    const float* __restrict__ a, const float* __restrict__ W1,
    const float* __restrict__ b1, float* __restrict__ aW1)
{
    __shared__ float Wsh[10][516];
    __shared__ float red[64][10][4];
    const int tid = threadIdx.x;
    for (int idx = tid; idx < 10 * 512; idx += 256) {
        int o = idx >> 9, k = idx & 511;
        Wsh[o][k] = W1[o * 1024 + k];
    }
    __syncthreads();
    const int r = tid >> 2, kq = tid & 3;
    const float* ar = a + ((size_t)blockIdx.x * 64 + r) * 512 + kq * 128;
    float acc[10] = {};
    for (int k = 0; k < 128; k += 4) {
        float4 v = *(const float4*)&ar[k];
        #pragma unroll
        for (int o = 0; o < 10; ++o) {
            float4 w = *(const float4*)&Wsh[o][kq * 128 + k];
            acc[o] += v.x * w.x + v.y * w.y + v.z * w.z + v.w * w.w;
        }
    }
    #pragma unroll
    for (int o = 0; o < 10; ++o) red[r][o][kq] = acc[o];
    __syncthreads();
    for (int idx = tid; idx < 640; idx += 256) {
        int rr = idx / 10, o = idx % 10;
        float s = red[rr][o][0] + red[rr][o][1] + red[rr][o][2] + red[rr][o][3] + b1[o];
        aW1[((size_t)blockIdx.x * 64 + rr) * 10 + o] = s;
    }
}

// ---------------------------------------------------------------------------
// Generic tiled GEMM: C[M,N] = A[M,K] @ B[N,K]^T + bias[N]
// ---------------------------------------------------------------------------
__global__ __launch_bounds__(256) void gemm_bt(
    const float* __restrict__ A, int lda,
    const float* __restrict__ B, int ldb,
    const float* __restrict__ bias,
    float* __restrict__ C, int ldc,
    int N, int K)
{
    __shared__ float As[16][72];
    __shared__ float Bs[16][72];
    const int tid = threadIdx.x;
    const int i0 = blockIdx.x * 64;
    const int j0 = blockIdx.y * 64;
    const int tx = tid & 15, ty = tid >> 4;
    const int m  = tid >> 2;
    const int k4 = (tid & 3) * 4;

    float acc[4][4] = {};
    for (int kb = 0; kb < K; kb += 16) {
        float4 va = *(const float4*)&A[(size_t)(i0 + m) * lda + kb + k4];
        float4 vb;
        if (j0 + m < N) vb = *(const float4*)&B[(size_t)(j0 + m) * ldb + kb + k4];
        else            vb = make_float4(0.f, 0.f, 0.f, 0.f);
        __syncthreads();
        As[k4+0][m] = va.x; As[k4+1][m] = va.y; As[k4+2][m] = va.z; As[k4+3][m] = va.w;
        Bs[k4+0][m] = vb.x; Bs[k4+1][m] = vb.y; Bs[k4+2][m] = vb.z; Bs[k4+3][m] = vb.w;
        __syncthreads();
        #pragma unroll
        for (int k = 0; k < 16; ++k) {
            float4 a4 = *(const float4*)&As[k][ty * 4];
            float4 b4 = *(const float4*)&Bs[k][tx * 4];
            acc[0][0] += a4.x*b4.x; acc[0][1] += a4.x*b4.y; acc[0][2] += a4.x*b4.z; acc[0][3] += a4.x*b4.w;
            acc[1][0] += a4.y*b4.x; acc[1][1] += a4.y*b4.y; acc[1][2] += a4.y*b4.z; acc[1][3] += a4.y*b4.w;
            acc[2][0] += a4.z*b4.x; acc[2][1] += a4.z*b4.y; acc[2][2] += a4.z*b4.z; acc[2][3] += a4.z*b4.w;
            acc[3][0] += a4.w*b4.x; acc[3][1] += a4.w*b4.y; acc[3][2] += a4.w*b4.z; acc[3][3] += a4.w*b4.w;
        }
    }
    #pragma unroll
    for (int r = 0; r < 4; ++r) {
        int row = i0 + ty * 4 + r;
        #pragma unroll
        for (int c = 0; c < 4; ++c) {
            int col = j0 + tx * 4 + c;
            if (col < N) {
                float v = acc[r][c] + (bias ? bias[col] : 0.f);
                C[(size_t)row * ldc + col] = v;
            }
        }
    }
}

// ---------------------------------------------------------------------------
// Fused attention: block per batch row i. Now also computes sW1 row in-block
// (was a separate 10-wide GEMM launch).
// ---------------------------------------------------------------------------
__global__ __launch_bounds__(256) void attn_kernel(
    const float* __restrict__ aW1,   // (m*Tx, 10), b1 already added
    const float* __restrict__ s_buf, // (m, 512)
    const float* __restrict__ W1,    // (10, 1024); cols 512.. are the s part
    const float* __restrict__ W2,    // (10,)
    const float* __restrict__ b2,    // (1,)
    const float* __restrict__ a,     // (m, Tx, 512)
    float* __restrict__ xcat)        // (m, 1024)
{
    __shared__ float sh_s[10];
    __shared__ float sh_w2[10];
    __shared__ float sred[160];
    __shared__ float red[256];
    __shared__ float al[256];
    const int i = blockIdx.x;
    const int tid = threadIdx.x;

    // sW1 row: sh_s[o] = dot(s_buf[i], W1[o, 512:1024])
    if (tid < 160) {
        int o = tid >> 4, part = tid & 15;
        const float* srow = s_buf + (size_t)i * 512;
        const float* wrow = W1 + o * 1024 + 512;
        float p = 0.f;
        for (int k = part; k < 512; k += 16) p += srow[k] * wrow[k];
        sred[tid] = p;
    }
    __syncthreads();
    if (tid < 10) {
        float v = 0.f;
        #pragma unroll
        for (int p = 0; p < 16; ++p) v += sred[tid * 16 + p];
        sh_s[tid] = v;
        sh_w2[tid] = W2[tid];
    }
    __syncthreads();

    float sum = b2[0];
    const float* ar = aW1 + ((size_t)i * TXN + tid) * 10;
    #pragma unroll
    for (int h = 0; h < 10; ++h) {
        float e = ftanh(ar[h] + sh_s[h]);
        sum += e * sh_w2[h];
    }
    float sc = fmaxf(sum, 0.f);

    red[tid] = sc;
    __syncthreads();
    for (int s = 128; s > 0; s >>= 1) {
        if (tid < s) red[tid] = fmaxf(red[tid], red[tid + s]);
        __syncthreads();
    }
    float mx = red[0];
    __syncthreads();
    float p = __expf(sc - mx);
    red[tid] = p;
    __syncthreads();
    for (int s = 128; s > 0; s >>= 1) {
        if (tid < s) red[tid] += red[tid + s];
        __syncthreads();
    }
    float inv = 1.f / red[0];
    al[tid] = p * inv;
    __syncthreads();

    float acc0 = 0.f, acc1 = 0.f;
    const float* arow = a + (size_t)i * TXN * NS;
    for (int t = 0; t < TXN; ++t) {
        float w = al[t];
        acc0 += w * arow[t * NS + tid];
        acc1 += w * arow[t * NS + 256 + tid];
    }
    xcat[(size_t)i * 1024 + tid]       = acc0;
    xcat[(size_t)i * 1024 + 256 + tid] = acc1;
}

// ---------------------------------------------------------------------------
// LSTM cell elementwise update from gate pre-activations.
// ---------------------------------------------------------------------------
__global__ __launch_bounds__(256) void cell_kernel(
    const float* __restrict__ g, float* __restrict__ c,
    float* __restrict__ s_buf, float* __restrict__ xcat)
{
    int idx = blockIdx.x * 256 + threadIdx.x;   // 256*512
    int i = idx >> 9, j = idx & 511;
    const float* gr = g + (size_t)i * 2048;
    float gi = fsigmoid(gr[j]);
    float gf = fsigmoid(gr[512 + j]);
    float gg = ftanh  (gr[1024 + j]);
    float go = fsigmoid(gr[1536 + j]);
    float cn = gf * c[idx] + gi * gg;
    c[idx] = cn;
    float h = go * ftanh(cn);
    s_buf[idx] = h;
    xcat[(size_t)i * 1024 + 512 + j] = h;
}

// Concatenate decoder LSTM weights: Wcat[r] = [Wc_ih[r] | Wc_hh[r]]
__global__ __launch_bounds__(256) void wcat_kernel(
    const float* __restrict__ Wc_ih, const float* __restrict__ Wc_hh,
    float* __restrict__ Wcat)
{
    int idx = blockIdx.x * 256 + threadIdx.x;   // 2048*1024
    int r = idx >> 10, k = idx & 1023;
    Wcat[idx] = (k < 512) ? Wc_ih[(size_t)r * 512 + k] : Wc_hh[(size_t)r * 512 + (k - 512)];
}

extern "C" void kernel_launch(void* const* d_in, const int* in_sizes, int n_in,
                              void* d_out, int out_size, void* d_ws, size_t ws_size,
                              hipStream_t stream)
{
    const float* X     = (const float*)d_in[0];
    const float* Wih_f = (const float*)d_in[1];
    const float* Whh_f = (const float*)d_in[2];
    const float* b_f   = (const float*)d_in[3];
    const float* Wih_b = (const float*)d_in[4];
    const float* Whh_b = (const float*)d_in[5];
    const float* b_b   = (const float*)d_in[6];
    const float* W1    = (const float*)d_in[7];
    const float* b1    = (const float*)d_in[8];
    const float* W2    = (const float*)d_in[9];
    const float* b2    = (const float*)d_in[10];
    const float* Wc_ih = (const float*)d_in[11];
    const float* Wc_hh = (const float*)d_in[12];
    const float* bc    = (const float*)d_in[13];
    const float* Wfc   = (const float*)d_in[14];
    const float* bfc   = (const float*)d_in[15];
    float* out = (float*)d_out;
    float* ws  = (float*)d_ws;

    // workspace layout (float offsets)
    float* c_buf = ws;                    // 256*512
    float* s_buf = ws + 131072;           // 256*512
    float* xcat  = ws + 262144;           // 256*1024  [ctx | s]
    float* a     = ws + 524288;           // 256*256*512
    float* aW1   = ws + 34078720;         // 65536*10
    float* Wcat  = ws + 34734080;         // 2048*1024
    float* g_buf = ws + 36833792;         // 256*2048
    unsigned int* bar = (unsigned int*)(ws + 37358080);  // 16 groups x 32 uints

    static int lds_raised = 0;
    if (!lds_raised) {
        hipFuncSetAttribute(reinterpret_cast<const void*>(encoder_kernel),
                            hipFuncAttributeMaxDynamicSharedMemorySize, ENC_LDS_BYTES);
        lds_raised = 1;
    }

    // zero c, s, xcat (contiguous 2 MB) and barrier counters
    hipMemsetAsync(c_buf, 0, (size_t)524288 * sizeof(float), stream);
    hipMemsetAsync(bar, 0, 16 * 32 * sizeof(unsigned int), stream);

    wcat_kernel<<<8192, 256, 0, stream>>>(Wc_ih, Wc_hh, Wcat);

    // persistent bidirectional LSTM encoder
    {
        void* args[] = { (void*)&X, (void*)&Wih_f, (void*)&Whh_f, (void*)&b_f,
                         (void*)&Wih_b, (void*)&Whh_b, (void*)&b_b, (void*)&a, (void*)&bar };
        hipLaunchCooperativeKernel(reinterpret_cast<void*>(encoder_kernel),
                                   dim3(256), dim3(256), args, ENC_LDS_BYTES, stream);
    }

    // aW1 = a @ W1[:, :512]^T + b1   (loop-invariant across decoder steps)
    attn_prep<<<1024, 256, 0, stream>>>(a, W1, b1, aW1);

    for (int ty = 0; ty < TYN; ++ty) {
        // attention (incl. fused sW1) + context -> xcat[:, :512]
        attn_kernel<<<256, 256, 0, stream>>>(aW1, s_buf, W1, W2, b2, a, xcat);
        // gates = xcat @ Wcat^T + bc
        gemm_bt<<<dim3(4, 32), 256, 0, stream>>>(xcat, 1024, Wcat, 1024, bc, g_buf, 2048, 2048, 1024);
        // cell update -> c, s (s also into xcat[:, 512:])
        cell_kernel<<<512, 256, 0, stream>>>(g_buf, c_buf, s_buf, xcat);
        // logits = s @ Wfc^T + bfc -> out[:, ty, :]
        gemm_bt<<<dim3(4, 16), 256, 0, stream>>>(s_buf, 512, Wfc, 512, bfc,
                                                 out + ty * VOCAB, TYN * VOCAB, VOCAB, 512);
    }
}

// Round 6
// 2711.189 us; speedup vs baseline: 7.5996x; 1.5959x over previous
//
#include <hip/hip_runtime.h>
#include <hip/hip_bf16.h>
#include <hip/hip_cooperative_groups.h>

namespace cg = cooperative_groups;

#define TXN 256   // Tx
#define NA 256    // n_a
#define NF 128    // features
#define NS 512    // n_s
#define TYN 10
#define VOCAB 1024

// ---- encoder LDS layout (split-bf16 planes) ----
#define A_STR 392   // bf16 elems/row: 384 + 8 pad (row = 784 B, 16B-aligned)
#define W_STR 392
#define WL_OFF (64 * W_STR)            // 25088
#define AH_OFF (2 * 64 * W_STR)        // 50176
#define AL_OFF (AH_OFF + 32 * A_STR)   // 62720
#define PRE_OFF_US (AL_OFF + 32 * A_STR)  // 75264 (ushort idx) -> byte 150528
#define ENC_LDS_BYTES (150528 + 32 * 68 * 4 + 64 * 4)   // 159,488 B

typedef __attribute__((ext_vector_type(8))) short bf16x8;
typedef __attribute__((ext_vector_type(4))) float f32x4;

__device__ __forceinline__ float fsigmoid(float x) { return 1.f / (1.f + __expf(-x)); }
__device__ __forceinline__ float ftanh(float x)    { return 1.f - 2.f / (1.f + __expf(2.f * x)); }

__device__ __forceinline__ void split_bf16(float v, unsigned short& hi, unsigned short& lo) {
    __hip_bfloat16 h = __float2bfloat16(v);
    float rem = v - __bfloat162float(h);
    __hip_bfloat16 l = __float2bfloat16(rem);
    hi = *reinterpret_cast<unsigned short*>(&h);
    lo = *reinterpret_cast<unsigned short*>(&l);
}

// ---------------------------------------------------------------------------
// Persistent bidirectional LSTM encoder — MFMA split-bf16, per-producer flags.
// 256 blocks x 256 threads, cooperative launch (co-residency only).
// Sync: 16 monotone flag slots per (dir,i-tile) group. Producer block jb sets
// slots[jb]=step+1 (plain agent store by tid0, after a __syncthreads that
// drains all waves' write-through h stores). Consumer thread `tid` needs h
// only from producer jb = tid>>4 (its A-panel column), so it polls just that
// slot, then loads its 32-row column with all loads in flight, converts, and
// stores to LDS. x(t+1) is staged between h-store and flag (latency hidden
// behind epilogue + drain). No RMW atomics, no fences, no grid.sync.
// ---------------------------------------------------------------------------
__global__ __launch_bounds__(256, 1) void encoder_kernel(
    const float* __restrict__ X,
    const float* __restrict__ Wih_f, const float* __restrict__ Whh_f, const float* __restrict__ b_f,
    const float* __restrict__ Wih_b, const float* __restrict__ Whh_b, const float* __restrict__ b_b,
    float* __restrict__ a, unsigned int* __restrict__ bar)
{
    extern __shared__ unsigned char smem_raw[];
    unsigned short* Wh  = (unsigned short*)smem_raw;
    unsigned short* Wl  = (unsigned short*)smem_raw + WL_OFF;
    unsigned short* Ahh = (unsigned short*)smem_raw + AH_OFF;
    unsigned short* All = (unsigned short*)smem_raw + AL_OFF;
    float* Pre = (float*)(smem_raw + (size_t)PRE_OFF_US * 2);   // [32][68]
    float* bsh = Pre + 32 * 68;                                  // [64]

    const int tid = threadIdx.x;
    const int dir = blockIdx.x & 1;
    const int bid = blockIdx.x >> 1;   // 0..127
    const int i0 = (bid >> 4) * 32;    // 8 i-tiles
    const int j0 = (bid & 15) * 16;    // 16 j-tiles
    const int grp = dir * 8 + (bid >> 4);
    const int myjb = bid & 15;
    unsigned int* slots = bar + grp * 16;   // 16 slots (64 B) per group

    const float* __restrict__ Wih = dir ? Wih_b : Wih_f;
    const float* __restrict__ Whh = dir ? Whh_b : Whh_f;
    const float* __restrict__ bv  = dir ? b_b  : b_f;

    const int jl = tid & 15;     // unit within j-tile (elementwise phase)
    const int ip = tid >> 4;     // 0..15
    const int iA = ip * 2;       // local batch row (even)

    // ---- one-time: weights (split to bf16 hi/lo) + bias into LDS ----
    if (tid < 64) bsh[tid] = bv[(tid >> 4) * NA + j0 + (tid & 15)];
    for (int r = 0; r < 64; ++r) {
        int row = (r >> 4) * NA + j0 + (r & 15);
        unsigned short hi, lo;
        split_bf16(Whh[(size_t)row * NA + tid], hi, lo);
        Wh[r * W_STR + tid] = hi;
        Wl[r * W_STR + tid] = lo;
        if (tid < NF) {
            split_bf16(Wih[(size_t)row * NF + tid], hi, lo);
            Wh[r * W_STR + 256 + tid] = hi;
            Wl[r * W_STR + 256 + tid] = lo;
        }
    }

    // ---- prologue: zero h-part of A, stage x(t0) ----
    #pragma unroll 4
    for (int r = 0; r < 32; ++r) {
        Ahh[r * A_STR + tid] = 0;
        All[r * A_STR + tid] = 0;
    }
    {
        const int t0 = dir ? (TXN - 1) : 0;
        const int kx = tid & 127;
        const int rbase = tid >> 7;
        #pragma unroll 4
        for (int rr = 0; rr < 16; ++rr) {
            int r = rr * 2 + rbase;
            float v = X[((size_t)(i0 + r) * TXN + t0) * NF + kx];
            unsigned short hi, lo;
            split_bf16(v, hi, lo);
            Ahh[r * A_STR + 256 + kx] = hi;
            All[r * A_STR + 256 + kx] = lo;
        }
    }

    float c0 = 0.f, c1 = 0.f;

    // MFMA wave assignment: wave wv -> row-tile (wv>>1), gate pair (wv&1)*2
    const int lane = tid & 63;
    const int wv   = tid >> 6;
    const int rt   = wv >> 1;
    const int g0   = (wv & 1) * 2;
    const int ln   = lane & 15;
    const int quad = lane >> 4;
    const unsigned short* pAh = Ahh + (rt * 16 + ln) * A_STR + quad * 8;
    const unsigned short* pAl = All + (rt * 16 + ln) * A_STR + quad * 8;
    const unsigned short* pW0h = Wh + (g0 * 16 + ln) * W_STR + quad * 8;
    const unsigned short* pW0l = Wl + (g0 * 16 + ln) * W_STR + quad * 8;
    const unsigned short* pW1h = pW0h + 16 * W_STR;
    const unsigned short* pW1l = pW0l + 16 * W_STR;

    for (int step = 0; step < TXN; ++step) {
        const int t = dir ? (TXN - 1 - step) : step;

        // ---- consumer: poll ONLY my producer's flag, then load my column ----
        if (step != 0) {
            const int tprev = dir ? (t + 1) : (t - 1);
            const int jb = tid >> 4;   // producer j-block of A-column `tid`
            while (__hip_atomic_load(&slots[jb], __ATOMIC_RELAXED,
                                     __HIP_MEMORY_SCOPE_AGENT) < (unsigned)step) {}
            float hv[32];
            #pragma unroll
            for (int r = 0; r < 32; ++r) {
                hv[r] = __hip_atomic_load(
                    &a[(((size_t)(i0 + r) * TXN + tprev) << 9) + dir * NA + tid],
                    __ATOMIC_RELAXED, __HIP_MEMORY_SCOPE_AGENT);
            }
            #pragma unroll
            for (int r = 0; r < 32; ++r) {
                unsigned short hi, lo;
                split_bf16(hv[r], hi, lo);
                Ahh[r * A_STR + tid] = hi;
                All[r * A_STR + tid] = lo;
            }
        }
        __syncthreads();

        // ---- MFMA phase: 2 C-tiles per wave, 4 chains (even/odd kc) ----
        f32x4 a0e = {0.f,0.f,0.f,0.f}, a0o = {0.f,0.f,0.f,0.f};
        f32x4 a1e = {0.f,0.f,0.f,0.f}, a1o = {0.f,0.f,0.f,0.f};
        #pragma unroll
        for (int kp = 0; kp < 6; ++kp) {
            {
                const int kc = kp * 2;
                bf16x8 fah = *(const bf16x8*)(pAh + kc * 32);
                bf16x8 fal = *(const bf16x8*)(pAl + kc * 32);
                bf16x8 w0h = *(const bf16x8*)(pW0h + kc * 32);
                bf16x8 w0l = *(const bf16x8*)(pW0l + kc * 32);
                bf16x8 w1h = *(const bf16x8*)(pW1h + kc * 32);
                bf16x8 w1l = *(const bf16x8*)(pW1l + kc * 32);
                a0e = __builtin_amdgcn_mfma_f32_16x16x32_bf16(fal, w0h, a0e, 0, 0, 0);
                a0e = __builtin_amdgcn_mfma_f32_16x16x32_bf16(fah, w0l, a0e, 0, 0, 0);
                a0e = __builtin_amdgcn_mfma_f32_16x16x32_bf16(fah, w0h, a0e, 0, 0, 0);
                a1e = __builtin_amdgcn_mfma_f32_16x16x32_bf16(fal, w1h, a1e, 0, 0, 0);
                a1e = __builtin_amdgcn_mfma_f32_16x16x32_bf16(fah, w1l, a1e, 0, 0, 0);
                a1e = __builtin_amdgcn_mfma_f32_16x16x32_bf16(fah, w1h, a1e, 0, 0, 0);
            }
            {
                const int kc = kp * 2 + 1;
                bf16x8 fah = *(const bf16x8*)(pAh + kc * 32);
                bf16x8 fal = *(const bf16x8*)(pAl + kc * 32);
                bf16x8 w0h = *(const bf16x8*)(pW0h + kc * 32);
                bf16x8 w0l = *(const bf16x8*)(pW0l + kc * 32);
                bf16x8 w1h = *(const bf16x8*)(pW1h + kc * 32);
                bf16x8 w1l = *(const bf16x8*)(pW1l + kc * 32);
                a0o = __builtin_amdgcn_mfma_f32_16x16x32_bf16(fal, w0h, a0o, 0, 0, 0);
                a0o = __builtin_amdgcn_mfma_f32_16x16x32_bf16(fah, w0l, a0o, 0, 0, 0);
                a0o = __builtin_amdgcn_mfma_f32_16x16x32_bf16(fah, w0h, a0o, 0, 0, 0);
                a1o = __builtin_amdgcn_mfma_f32_16x16x32_bf16(fal, w1h, a1o, 0, 0, 0);
                a1o = __builtin_amdgcn_mfma_f32_16x16x32_bf16(fah, w1l, a1o, 0, 0, 0);
                a1o = __builtin_amdgcn_mfma_f32_16x16x32_bf16(fah, w1h, a1o, 0, 0, 0);
            }
        }
        // C/D layout: col = lane&15 (gate-row within tile), row = quad*4+reg
        #pragma unroll
        for (int reg = 0; reg < 4; ++reg) {
            int prow = rt * 16 + quad * 4 + reg;
            Pre[prow * 68 + g0 * 16 + ln]       = a0e[reg] + a0o[reg];
            Pre[prow * 68 + (g0 + 1) * 16 + ln] = a1e[reg] + a1o[reg];
        }
        __syncthreads();

        // ---- elementwise phase: per-thread (2 rows x 1 unit), c in regs ----
        float h0, h1;
        {
            float gi = fsigmoid(Pre[iA * 68 +      jl] + bsh[jl]);
            float gf = fsigmoid(Pre[iA * 68 + 16 + jl] + bsh[16 + jl]);
            float gg = ftanh  (Pre[iA * 68 + 32 + jl] + bsh[32 + jl]);
            float go = fsigmoid(Pre[iA * 68 + 48 + jl] + bsh[48 + jl]);
            c0 = gf * c0 + gi * gg;
            h0 = go * ftanh(c0);
        }
        {
            float gi = fsigmoid(Pre[(iA + 1) * 68 +      jl] + bsh[jl]);
            float gf = fsigmoid(Pre[(iA + 1) * 68 + 16 + jl] + bsh[16 + jl]);
            float gg = ftanh  (Pre[(iA + 1) * 68 + 32 + jl] + bsh[32 + jl]);
            float go = fsigmoid(Pre[(iA + 1) * 68 + 48 + jl] + bsh[48 + jl]);
            c1 = gf * c1 + gi * gg;
            h1 = go * ftanh(c1);
        }
        // write-through agent-scope h stores
        __hip_atomic_store(
            &a[(((size_t)(i0 + iA)     * TXN + t) << 9) + dir * NA + j0 + jl],
            h0, __ATOMIC_RELAXED, __HIP_MEMORY_SCOPE_AGENT);
        __hip_atomic_store(
            &a[(((size_t)(i0 + iA + 1) * TXN + t) << 9) + dir * NA + j0 + jl],
            h1, __ATOMIC_RELAXED, __HIP_MEMORY_SCOPE_AGENT);

        if (step != TXN - 1) {
            // ---- stage x(t_next): latency hides behind epilogue + drain ----
            {
                const int tn = dir ? (t - 1) : (t + 1);
                const int kx = tid & 127;
                const int rbase = tid >> 7;
                #pragma unroll 4
                for (int rr = 0; rr < 16; ++rr) {
                    int r = rr * 2 + rbase;
                    float v = X[((size_t)(i0 + r) * TXN + tn) * NF + kx];
                    unsigned short hi, lo;
                    split_bf16(v, hi, lo);
                    Ahh[r * A_STR + 256 + kx] = hi;
                    All[r * A_STR + 256 + kx] = lo;
                }
            }
            __syncthreads();   // all waves' h stores drained (vmcnt0) + x staged
            if (tid == 0) {
                __hip_atomic_store(&slots[myjb], (unsigned)(step + 1),
                                   __ATOMIC_RELAXED, __HIP_MEMORY_SCOPE_AGENT);
            }
        }
    }
}

// ---------------------------------------------------------------------------
// Tall-skinny: aW1[m*Tx][10] = a[m*Tx][512] @ W1[:, :512]^T + b1
// ---------------------------------------------------------------------------
__global__ __launch_bounds__(256) void attn_prep(
    const float* __restrict__ a, const float* __restrict__ W1,
    const float* __restrict__ b1, float* __restrict__ aW1)
{
    __shared__ float Wsh[10][516];
    __shared__ float red[64][10][4];
    const int tid = threadIdx.x;
    for (int idx = tid; idx < 10 * 512; idx += 256) {
        int o = idx >> 9, k = idx & 511;
        Wsh[o][k] = W1[o * 1024 + k];
    }
    __syncthreads();
    const int r = tid >> 2, kq = tid & 3;
    const float* ar = a + ((size_t)blockIdx.x * 64 + r) * 512 + kq * 128;
    float acc[10] = {};
    for (int k = 0; k < 128; k += 4) {
        float4 v = *(const float4*)&ar[k];
        #pragma unroll
        for (int o = 0; o < 10; ++o) {
            float4 w = *(const float4*)&Wsh[o][kq * 128 + k];
            acc[o] += v.x * w.x + v.y * w.y + v.z * w.z + v.w * w.w;
        }
    }
    #pragma unroll
    for (int o = 0; o < 10; ++o) red[r][o][kq] = acc[o];
    __syncthreads();
    for (int idx = tid; idx < 640; idx += 256) {
        int rr = idx / 10, o = idx % 10;
        float s = red[rr][o][0] + red[rr][o][1] + red[rr][o][2] + red[rr][o][3] + b1[o];
        aW1[((size_t)blockIdx.x * 64 + rr) * 10 + o] = s;
    }
}

// ---------------------------------------------------------------------------
// Generic tiled GEMM: C[M,N] = A[M,K] @ B[N,K]^T + bias[N]
// ---------------------------------------------------------------------------
__global__ __launch_bounds__(256) void gemm_bt(
    const float* __restrict__ A, int lda,
    const float* __restrict__ B, int ldb,
    const float* __restrict__ bias,
    float* __restrict__ C, int ldc,
    int N, int K)
{
    __shared__ float As[16][72];
    __shared__ float Bs[16][72];
    const int tid = threadIdx.x;
    const int i0 = blockIdx.x * 64;
    const int j0 = blockIdx.y * 64;
    const int tx = tid & 15, ty = tid >> 4;
    const int m  = tid >> 2;
    const int k4 = (tid & 3) * 4;

    float acc[4][4] = {};
    for (int kb = 0; kb < K; kb += 16) {
        float4 va = *(const float4*)&A[(size_t)(i0 + m) * lda + kb + k4];
        float4 vb;
        if (j0 + m < N) vb = *(const float4*)&B[(size_t)(j0 + m) * ldb + kb + k4];
        else            vb = make_float4(0.f, 0.f, 0.f, 0.f);
        __syncthreads();
        As[k4+0][m] = va.x; As[k4+1][m] = va.y; As[k4+2][m] = va.z; As[k4+3][m] = va.w;
        Bs[k4+0][m] = vb.x; Bs[k4+1][m] = vb.y; Bs[k4+2][m] = vb.z; Bs[k4+3][m] = vb.w;
        __syncthreads();
        #pragma unroll
        for (int k = 0; k < 16; ++k) {
            float4 a4 = *(const float4*)&As[k][ty * 4];
            float4 b4 = *(const float4*)&Bs[k][tx * 4];
            acc[0][0] += a4.x*b4.x; acc[0][1] += a4.x*b4.y; acc[0][2] += a4.x*b4.z; acc[0][3] += a4.x*b4.w;
            acc[1][0] += a4.y*b4.x; acc[1][1] += a4.y*b4.y; acc[1][2] += a4.y*b4.z; acc[1][3] += a4.y*b4.w;
            acc[2][0] += a4.z*b4.x; acc[2][1] += a4.z*b4.y; acc[2][2] += a4.z*b4.z; acc[2][3] += a4.z*b4.w;
            acc[3][0] += a4.w*b4.x; acc[3][1] += a4.w*b4.y; acc[3][2] += a4.w*b4.z; acc[3][3] += a4.w*b4.w;
        }
    }
    #pragma unroll
    for (int r = 0; r < 4; ++r) {
        int row = i0 + ty * 4 + r;
        #pragma unroll
        for (int c = 0; c < 4; ++c) {
            int col = j0 + tx * 4 + c;
            if (col < N) {
                float v = acc[r][c] + (bias ? bias[col] : 0.f);
                C[(size_t)row * ldc + col] = v;
            }
        }
    }
}

// ---------------------------------------------------------------------------
// Fused attention: block per batch row i (incl. in-block sW1).
// ---------------------------------------------------------------------------
__global__ __launch_bounds__(256) void attn_kernel(
    const float* __restrict__ aW1,   // (m*Tx, 10), b1 already added
    const float* __restrict__ s_buf, // (m, 512)
    const float* __restrict__ W1,    // (10, 1024); cols 512.. are the s part
    const float* __restrict__ W2,    // (10,)
    const float* __restrict__ b2,    // (1,)
    const float* __restrict__ a,     // (m, Tx, 512)
    float* __restrict__ xcat)        // (m, 1024)
{
    __shared__ float sh_s[10];
    __shared__ float sh_w2[10];
    __shared__ float sred[160];
    __shared__ float red[256];
    __shared__ float al[256];
    const int i = blockIdx.x;
    const int tid = threadIdx.x;

    if (tid < 160) {
        int o = tid >> 4, part = tid & 15;
        const float* srow = s_buf + (size_t)i * 512;
        const float* wrow = W1 + o * 1024 + 512;
        float p = 0.f;
        for (int k = part; k < 512; k += 16) p += srow[k] * wrow[k];
        sred[tid] = p;
    }
    __syncthreads();
    if (tid < 10) {
        float v = 0.f;
        #pragma unroll
        for (int p = 0; p < 16; ++p) v += sred[tid * 16 + p];
        sh_s[tid] = v;
        sh_w2[tid] = W2[tid];
    }
    __syncthreads();

    float sum = b2[0];
    const float* ar = aW1 + ((size_t)i * TXN + tid) * 10;
    #pragma unroll
    for (int h = 0; h < 10; ++h) {
        float e = ftanh(ar[h] + sh_s[h]);
        sum += e * sh_w2[h];
    }
    float sc = fmaxf(sum, 0.f);

    red[tid] = sc;
    __syncthreads();
    for (int s = 128; s > 0; s >>= 1) {
        if (tid < s) red[tid] = fmaxf(red[tid], red[tid + s]);
        __syncthreads();
    }
    float mx = red[0];
    __syncthreads();
    float p = __expf(sc - mx);
    red[tid] = p;
    __syncthreads();
    for (int s = 128; s > 0; s >>= 1) {
        if (tid < s) red[tid] += red[tid + s];
        __syncthreads();
    }
    float inv = 1.f / red[0];
    al[tid] = p * inv;
    __syncthreads();

    float acc0 = 0.f, acc1 = 0.f;
    const float* arow = a + (size_t)i * TXN * NS;
    for (int t = 0; t < TXN; ++t) {
        float w = al[t];
        acc0 += w * arow[t * NS + tid];
        acc1 += w * arow[t * NS + 256 + tid];
    }
    xcat[(size_t)i * 1024 + tid]       = acc0;
    xcat[(size_t)i * 1024 + 256 + tid] = acc1;
}

// ---------------------------------------------------------------------------
// LSTM cell elementwise update from gate pre-activations.
// ---------------------------------------------------------------------------
__global__ __launch_bounds__(256) void cell_kernel(
    const float* __restrict__ g, float* __restrict__ c,
    float* __restrict__ s_buf, float* __restrict__ xcat)
{
    int idx = blockIdx.x * 256 + threadIdx.x;   // 256*512
    int i = idx >> 9, j = idx & 511;
    const float* gr = g + (size_t)i * 2048;
    float gi = fsigmoid(gr[j]);
    float gf = fsigmoid(gr[512 + j]);
    float gg = ftanh  (gr[1024 + j]);
    float go = fsigmoid(gr[1536 + j]);
    float cn = gf * c[idx] + gi * gg;
    c[idx] = cn;
    float h = go * ftanh(cn);
    s_buf[idx] = h;
    xcat[(size_t)i * 1024 + 512 + j] = h;
}

// Concatenate decoder LSTM weights: Wcat[r] = [Wc_ih[r] | Wc_hh[r]]
__global__ __launch_bounds__(256) void wcat_kernel(
    const float* __restrict__ Wc_ih, const float* __restrict__ Wc_hh,
    float* __restrict__ Wcat)
{
    int idx = blockIdx.x * 256 + threadIdx.x;   // 2048*1024
    int r = idx >> 10, k = idx & 1023;
    Wcat[idx] = (k < 512) ? Wc_ih[(size_t)r * 512 + k] : Wc_hh[(size_t)r * 512 + (k - 512)];
}

extern "C" void kernel_launch(void* const* d_in, const int* in_sizes, int n_in,
                              void* d_out, int out_size, void* d_ws, size_t ws_size,
                              hipStream_t stream)
{
    const float* X     = (const float*)d_in[0];
    const float* Wih_f = (const float*)d_in[1];
    const float* Whh_f = (const float*)d_in[2];
    const float* b_f   = (const float*)d_in[3];
    const float* Wih_b = (const float*)d_in[4];
    const float* Whh_b = (const float*)d_in[5];
    const float* b_b   = (const float*)d_in[6];
    const float* W1    = (const float*)d_in[7];
    const float* b1    = (const float*)d_in[8];
    const float* W2    = (const float*)d_in[9];
    const float* b2    = (const float*)d_in[10];
    const float* Wc_ih = (const float*)d_in[11];
    const float* Wc_hh = (const float*)d_in[12];
    const float* bc    = (const float*)d_in[13];
    const float* Wfc   = (const float*)d_in[14];
    const float* bfc   = (const float*)d_in[15];
    float* out = (float*)d_out;
    float* ws  = (float*)d_ws;

    // workspace layout (float offsets)
    float* c_buf = ws;                    // 256*512
    float* s_buf = ws + 131072;           // 256*512
    float* xcat  = ws + 262144;           // 256*1024  [ctx | s]
    float* a     = ws + 524288;           // 256*256*512
    float* aW1   = ws + 34078720;         // 65536*10
    float* Wcat  = ws + 34734080;         // 2048*1024
    float* g_buf = ws + 36833792;         // 256*2048
    unsigned int* bar = (unsigned int*)(ws + 37358080);  // 16 groups x 16 uints

    static int lds_raised = 0;
    if (!lds_raised) {
        hipFuncSetAttribute(reinterpret_cast<const void*>(encoder_kernel),
                            hipFuncAttributeMaxDynamicSharedMemorySize, ENC_LDS_BYTES);
        lds_raised = 1;
    }

    // zero c, s, xcat (contiguous 2 MB) and flag slots
    hipMemsetAsync(c_buf, 0, (size_t)524288 * sizeof(float), stream);
    hipMemsetAsync(bar, 0, 16 * 16 * sizeof(unsigned int), stream);

    wcat_kernel<<<8192, 256, 0, stream>>>(Wc_ih, Wc_hh, Wcat);

    // persistent bidirectional LSTM encoder
    {
        void* args[] = { (void*)&X, (void*)&Wih_f, (void*)&Whh_f, (void*)&b_f,
                         (void*)&Wih_b, (void*)&Whh_b, (void*)&b_b, (void*)&a, (void*)&bar };
        hipLaunchCooperativeKernel(reinterpret_cast<void*>(encoder_kernel),
                                   dim3(256), dim3(256), args, ENC_LDS_BYTES, stream);
    }

    // aW1 = a @ W1[:, :512]^T + b1   (loop-invariant across decoder steps)
    attn_prep<<<1024, 256, 0, stream>>>(a, W1, b1, aW1);

    for (int ty = 0; ty < TYN; ++ty) {
        // attention (incl. fused sW1) + context -> xcat[:, :512]
        attn_kernel<<<256, 256, 0, stream>>>(aW1, s_buf, W1, W2, b2, a, xcat);
        // gates = xcat @ Wcat^T + bc
        gemm_bt<<<dim3(4, 32), 256, 0, stream>>>(xcat, 1024, Wcat, 1024, bc, g_buf, 2048, 2048, 1024);
        // cell update -> c, s (s also into xcat[:, 512:])
        cell_kernel<<<512, 256, 0, stream>>>(g_buf, c_buf, s_buf, xcat);
        // logits = s @ Wfc^T + bfc -> out[:, ty, :]
        gemm_bt<<<dim3(4, 16), 256, 0, stream>>>(s_buf, 512, Wfc, 512, bfc,
                                                 out + ty * VOCAB, TYN * VOCAB, VOCAB, 512);
    }
}

// Round 7
// 2184.330 us; speedup vs baseline: 9.4327x; 1.2412x over previous
//
#include <hip/hip_runtime.h>
#include <hip/hip_bf16.h>
#include <hip/hip_cooperative_groups.h>

namespace cg = cooperative_groups;

#define TXN 256   // Tx
#define NA 256    // n_a
#define NF 128    // features
#define NS 512    // n_s
#define TYN 10
#define VOCAB 1024

// ---- encoder LDS layout (split-bf16 planes) ----
#define A_STR 392
#define W_STR 392
#define WL_OFF (64 * W_STR)
#define AH_OFF (2 * 64 * W_STR)
#define AL_OFF (AH_OFF + 32 * A_STR)
#define PRE_OFF_US (AL_OFF + 32 * A_STR)
#define ENC_LDS_BYTES (150528 + 32 * 68 * 4 + 64 * 4)   // 159,488 B

// ---- decoder MFMA-GEMM LDS layout (ushort indices), K-chunk = 256 ----
#define D_STR 264                        // 256 + 8 pad
#define D_WH 0
#define D_WL (64 * D_STR)                // 16896
#define D_AH (2 * 64 * D_STR)            // 33792
#define D_AL (D_AH + 32 * D_STR)         // 42240
#define D_PRE_US (D_AL + 32 * D_STR)     // 50688 -> byte 101376
#define DEC_LDS_BYTES (101376 + 32 * 68 * 4 + 64 * 4)   // 110,336 B

typedef __attribute__((ext_vector_type(8))) short bf16x8;
typedef __attribute__((ext_vector_type(4))) float f32x4;

__device__ __forceinline__ float fsigmoid(float x) { return 1.f / (1.f + __expf(-x)); }
__device__ __forceinline__ float ftanh(float x)    { return 1.f - 2.f / (1.f + __expf(2.f * x)); }

__device__ __forceinline__ void split_bf16(float v, unsigned short& hi, unsigned short& lo) {
    __hip_bfloat16 h = __float2bfloat16(v);
    float rem = v - __bfloat162float(h);
    __hip_bfloat16 l = __float2bfloat16(rem);
    hi = *reinterpret_cast<unsigned short*>(&h);
    lo = *reinterpret_cast<unsigned short*>(&l);
}

// ---------------------------------------------------------------------------
// Persistent bidirectional LSTM encoder — MFMA split-bf16, per-producer flags.
// R7 change: flag store happens right after the h-store drain; x(t+1) staging
// moved AFTER the flag so its global-load latency is off the exchange path.
// ---------------------------------------------------------------------------
__global__ __launch_bounds__(256, 1) void encoder_kernel(
    const float* __restrict__ X,
    const float* __restrict__ Wih_f, const float* __restrict__ Whh_f, const float* __restrict__ b_f,
    const float* __restrict__ Wih_b, const float* __restrict__ Whh_b, const float* __restrict__ b_b,
    float* __restrict__ a, unsigned int* __restrict__ bar)
{
    extern __shared__ unsigned char smem_raw[];
    unsigned short* Wh  = (unsigned short*)smem_raw;
    unsigned short* Wl  = (unsigned short*)smem_raw + WL_OFF;
    unsigned short* Ahh = (unsigned short*)smem_raw + AH_OFF;
    unsigned short* All = (unsigned short*)smem_raw + AL_OFF;
    float* Pre = (float*)(smem_raw + (size_t)PRE_OFF_US * 2);   // [32][68]
    float* bsh = Pre + 32 * 68;                                  // [64]

    const int tid = threadIdx.x;
    const int dir = blockIdx.x & 1;
    const int bid = blockIdx.x >> 1;
    const int i0 = (bid >> 4) * 32;
    const int j0 = (bid & 15) * 16;
    const int grp = dir * 8 + (bid >> 4);
    const int myjb = bid & 15;
    unsigned int* slots = bar + grp * 16;

    const float* __restrict__ Wih = dir ? Wih_b : Wih_f;
    const float* __restrict__ Whh = dir ? Whh_b : Whh_f;
    const float* __restrict__ bv  = dir ? b_b  : b_f;

    const int jl = tid & 15;
    const int ip = tid >> 4;
    const int iA = ip * 2;

    if (tid < 64) bsh[tid] = bv[(tid >> 4) * NA + j0 + (tid & 15)];
    for (int r = 0; r < 64; ++r) {
        int row = (r >> 4) * NA + j0 + (r & 15);
        unsigned short hi, lo;
        split_bf16(Whh[(size_t)row * NA + tid], hi, lo);
        Wh[r * W_STR + tid] = hi;
        Wl[r * W_STR + tid] = lo;
        if (tid < NF) {
            split_bf16(Wih[(size_t)row * NF + tid], hi, lo);
            Wh[r * W_STR + 256 + tid] = hi;
            Wl[r * W_STR + 256 + tid] = lo;
        }
    }

    // prologue: zero h-part of A, stage x(t0)
    #pragma unroll 4
    for (int r = 0; r < 32; ++r) {
        Ahh[r * A_STR + tid] = 0;
        All[r * A_STR + tid] = 0;
    }
    {
        const int t0 = dir ? (TXN - 1) : 0;
        const int kx = tid & 127;
        const int rbase = tid >> 7;
        #pragma unroll 4
        for (int rr = 0; rr < 16; ++rr) {
            int r = rr * 2 + rbase;
            float v = X[((size_t)(i0 + r) * TXN + t0) * NF + kx];
            unsigned short hi, lo;
            split_bf16(v, hi, lo);
            Ahh[r * A_STR + 256 + kx] = hi;
            All[r * A_STR + 256 + kx] = lo;
        }
    }

    float c0 = 0.f, c1 = 0.f;

    const int lane = tid & 63;
    const int wv   = tid >> 6;
    const int rt   = wv >> 1;
    const int g0   = (wv & 1) * 2;
    const int ln   = lane & 15;
    const int quad = lane >> 4;
    const unsigned short* pAh = Ahh + (rt * 16 + ln) * A_STR + quad * 8;
    const unsigned short* pAl = All + (rt * 16 + ln) * A_STR + quad * 8;
    const unsigned short* pW0h = Wh + (g0 * 16 + ln) * W_STR + quad * 8;
    const unsigned short* pW0l = Wl + (g0 * 16 + ln) * W_STR + quad * 8;
    const unsigned short* pW1h = pW0h + 16 * W_STR;
    const unsigned short* pW1l = pW0l + 16 * W_STR;

    for (int step = 0; step < TXN; ++step) {
        const int t = dir ? (TXN - 1 - step) : step;

        if (step != 0) {
            const int tprev = dir ? (t + 1) : (t - 1);
            const int jb = tid >> 4;
            while (__hip_atomic_load(&slots[jb], __ATOMIC_RELAXED,
                                     __HIP_MEMORY_SCOPE_AGENT) < (unsigned)step) {}
            float hv[32];
            #pragma unroll
            for (int r = 0; r < 32; ++r) {
                hv[r] = __hip_atomic_load(
                    &a[(((size_t)(i0 + r) * TXN + tprev) << 9) + dir * NA + tid],
                    __ATOMIC_RELAXED, __HIP_MEMORY_SCOPE_AGENT);
            }
            #pragma unroll
            for (int r = 0; r < 32; ++r) {
                unsigned short hi, lo;
                split_bf16(hv[r], hi, lo);
                Ahh[r * A_STR + tid] = hi;
                All[r * A_STR + tid] = lo;
            }
        }
        __syncthreads();

        f32x4 a0e = {0.f,0.f,0.f,0.f}, a0o = {0.f,0.f,0.f,0.f};
        f32x4 a1e = {0.f,0.f,0.f,0.f}, a1o = {0.f,0.f,0.f,0.f};
        #pragma unroll
        for (int kp = 0; kp < 6; ++kp) {
            {
                const int kc = kp * 2;
                bf16x8 fah = *(const bf16x8*)(pAh + kc * 32);
                bf16x8 fal = *(const bf16x8*)(pAl + kc * 32);
                bf16x8 w0h = *(const bf16x8*)(pW0h + kc * 32);
                bf16x8 w0l = *(const bf16x8*)(pW0l + kc * 32);
                bf16x8 w1h = *(const bf16x8*)(pW1h + kc * 32);
                bf16x8 w1l = *(const bf16x8*)(pW1l + kc * 32);
                a0e = __builtin_amdgcn_mfma_f32_16x16x32_bf16(fal, w0h, a0e, 0, 0, 0);
                a0e = __builtin_amdgcn_mfma_f32_16x16x32_bf16(fah, w0l, a0e, 0, 0, 0);
                a0e = __builtin_amdgcn_mfma_f32_16x16x32_bf16(fah, w0h, a0e, 0, 0, 0);
                a1e = __builtin_amdgcn_mfma_f32_16x16x32_bf16(fal, w1h, a1e, 0, 0, 0);
                a1e = __builtin_amdgcn_mfma_f32_16x16x32_bf16(fah, w1l, a1e, 0, 0, 0);
                a1e = __builtin_amdgcn_mfma_f32_16x16x32_bf16(fah, w1h, a1e, 0, 0, 0);
            }
            {
                const int kc = kp * 2 + 1;
                bf16x8 fah = *(const bf16x8*)(pAh + kc * 32);
                bf16x8 fal = *(const bf16x8*)(pAl + kc * 32);
                bf16x8 w0h = *(const bf16x8*)(pW0h + kc * 32);
                bf16x8 w0l = *(const bf16x8*)(pW0l + kc * 32);
                bf16x8 w1h = *(const bf16x8*)(pW1h + kc * 32);
                bf16x8 w1l = *(const bf16x8*)(pW1l + kc * 32);
                a0o = __builtin_amdgcn_mfma_f32_16x16x32_bf16(fal, w0h, a0o, 0, 0, 0);
                a0o = __builtin_amdgcn_mfma_f32_16x16x32_bf16(fah, w0l, a0o, 0, 0, 0);
                a0o = __builtin_amdgcn_mfma_f32_16x16x32_bf16(fah, w0h, a0o, 0, 0, 0);
                a1o = __builtin_amdgcn_mfma_f32_16x16x32_bf16(fal, w1h, a1o, 0, 0, 0);
                a1o = __builtin_amdgcn_mfma_f32_16x16x32_bf16(fah, w1l, a1o, 0, 0, 0);
                a1o = __builtin_amdgcn_mfma_f32_16x16x32_bf16(fah, w1h, a1o, 0, 0, 0);
            }
        }
        #pragma unroll
        for (int reg = 0; reg < 4; ++reg) {
            int prow = rt * 16 + quad * 4 + reg;
            Pre[prow * 68 + g0 * 16 + ln]       = a0e[reg] + a0o[reg];
            Pre[prow * 68 + (g0 + 1) * 16 + ln] = a1e[reg] + a1o[reg];
        }
        __syncthreads();

        float h0, h1;
        {
            float gi = fsigmoid(Pre[iA * 68 +      jl] + bsh[jl]);
            float gf = fsigmoid(Pre[iA * 68 + 16 + jl] + bsh[16 + jl]);
            float gg = ftanh  (Pre[iA * 68 + 32 + jl] + bsh[32 + jl]);
            float go = fsigmoid(Pre[iA * 68 + 48 + jl] + bsh[48 + jl]);
            c0 = gf * c0 + gi * gg;
            h0 = go * ftanh(c0);
        }
        {
            float gi = fsigmoid(Pre[(iA + 1) * 68 +      jl] + bsh[jl]);
            float gf = fsigmoid(Pre[(iA + 1) * 68 + 16 + jl] + bsh[16 + jl]);
            float gg = ftanh  (Pre[(iA + 1) * 68 + 32 + jl] + bsh[32 + jl]);
            float go = fsigmoid(Pre[(iA + 1) * 68 + 48 + jl] + bsh[48 + jl]);
            c1 = gf * c1 + gi * gg;
            h1 = go * ftanh(c1);
        }
        __hip_atomic_store(
            &a[(((size_t)(i0 + iA)     * TXN + t) << 9) + dir * NA + j0 + jl],
            h0, __ATOMIC_RELAXED, __HIP_MEMORY_SCOPE_AGENT);
        __hip_atomic_store(
            &a[(((size_t)(i0 + iA + 1) * TXN + t) << 9) + dir * NA + j0 + jl],
            h1, __ATOMIC_RELAXED, __HIP_MEMORY_SCOPE_AGENT);

        if (step != TXN - 1) {
            __syncthreads();   // drains all waves' h stores (vmcnt0 before s_barrier)
            if (tid == 0) {
                __hip_atomic_store(&slots[myjb], (unsigned)(step + 1),
                                   __ATOMIC_RELAXED, __HIP_MEMORY_SCOPE_AGENT);
            }
            // stage x(t_next) AFTER the flag — off the exchange critical path
            {
                const int tn = dir ? (t - 1) : (t + 1);
                const int kx = tid & 127;
                const int rbase = tid >> 7;
                #pragma unroll 4
                for (int rr = 0; rr < 16; ++rr) {
                    int r = rr * 2 + rbase;
                    float v = X[((size_t)(i0 + r) * TXN + tn) * NF + kx];
                    unsigned short hi, lo;
                    split_bf16(v, hi, lo);
                    Ahh[r * A_STR + 256 + kx] = hi;
                    All[r * A_STR + 256 + kx] = lo;
                }
            }
        }
    }
}

// ---------------------------------------------------------------------------
// Weight split kernels: fp32 -> bf16 hi/lo planes.
// Wcat row r = [Wc_ih[r] | Wc_hh[r]], (2048,1024). Wfc (1024,512).
// ---------------------------------------------------------------------------
__global__ __launch_bounds__(256) void wsplit_cat(
    const float* __restrict__ Wc_ih, const float* __restrict__ Wc_hh,
    unsigned short* __restrict__ Wh, unsigned short* __restrict__ Wl)
{
    int idx = blockIdx.x * 256 + threadIdx.x;   // 2048*1024
    int r = idx >> 10, k = idx & 1023;
    float v = (k < 512) ? Wc_ih[(size_t)r * 512 + k] : Wc_hh[(size_t)r * 512 + (k - 512)];
    unsigned short hi, lo;
    split_bf16(v, hi, lo);
    Wh[idx] = hi; Wl[idx] = lo;
}

__global__ __launch_bounds__(256) void wsplit_fc(
    const float* __restrict__ Wfc,
    unsigned short* __restrict__ Wh, unsigned short* __restrict__ Wl)
{
    int idx = blockIdx.x * 256 + threadIdx.x;   // 1024*512
    unsigned short hi, lo;
    split_bf16(Wfc[idx], hi, lo);
    Wh[idx] = hi; Wl[idx] = lo;
}

// ---------------------------------------------------------------------------
// Decoder gates GEMM (MFMA split-bf16) + fused LSTM cell epilogue.
// grid (8, 32): 32-row M-tile x (16 units x 4 gates) N-tile. K=1024, 4 chunks.
// ---------------------------------------------------------------------------
__global__ __launch_bounds__(256, 1) void gates_kernel(
    const float* __restrict__ xcat,          // (256, 1024) [ctx | s]
    const unsigned short* __restrict__ Wch,  // (2048, 1024) hi plane
    const unsigned short* __restrict__ Wcl,  // lo plane
    const float* __restrict__ bc,            // (2048,)
    float* __restrict__ c_buf,               // (256, 512)
    float* __restrict__ s_buf,               // (256, 512)
    float* __restrict__ xc_out)              // xcat s-half update
{
    extern __shared__ unsigned char smem_raw[];
    unsigned short* Wh = (unsigned short*)smem_raw + D_WH;
    unsigned short* Wl = (unsigned short*)smem_raw + D_WL;
    unsigned short* Ah = (unsigned short*)smem_raw + D_AH;
    unsigned short* Al = (unsigned short*)smem_raw + D_AL;
    float* Pre = (float*)(smem_raw + (size_t)D_PRE_US * 2);   // [32][68]
    float* bsh = Pre + 32 * 68;                                // [64]

    const int tid = threadIdx.x;
    const int i0 = blockIdx.x * 32;
    const int j0 = blockIdx.y * 16;

    if (tid < 64) bsh[tid] = bc[(tid >> 4) * 512 + j0 + (tid & 15)];

    const int lane = tid & 63;
    const int wv   = tid >> 6;
    const int rt   = wv >> 1;
    const int g0   = (wv & 1) * 2;
    const int ln   = lane & 15;
    const int quad = lane >> 4;
    const unsigned short* pAh = Ah + (rt * 16 + ln) * D_STR + quad * 8;
    const unsigned short* pAl = Al + (rt * 16 + ln) * D_STR + quad * 8;
    const unsigned short* pW0h = Wh + (g0 * 16 + ln) * D_STR + quad * 8;
    const unsigned short* pW0l = Wl + (g0 * 16 + ln) * D_STR + quad * 8;
    const unsigned short* pW1h = pW0h + 16 * D_STR;
    const unsigned short* pW1l = pW0l + 16 * D_STR;

    // W staging indices: thread -> (row rW, 64-ushort quarter qW)
    const int rW = tid >> 2;
    const int qW = (tid & 3) * 64;
    const int rowg = (rW >> 4) * 512 + j0 + (rW & 15);   // gate-interleaved

    f32x4 a0 = {0.f,0.f,0.f,0.f}, a1 = {0.f,0.f,0.f,0.f};

    for (int ch = 0; ch < 4; ++ch) {
        const int kc0 = ch * 256;
        __syncthreads();   // protect LDS from previous chunk's MFMA reads
        // stage A chunk (32 x 256 fp32 -> hi/lo)
        #pragma unroll 8
        for (int r = 0; r < 32; ++r) {
            float v = xcat[(size_t)(i0 + r) * 1024 + kc0 + tid];
            unsigned short hi, lo;
            split_bf16(v, hi, lo);
            Ah[r * D_STR + tid] = hi;
            Al[r * D_STR + tid] = lo;
        }
        // stage W chunk (64 rows x 256 ushorts per plane)
        {
            const size_t base = (size_t)rowg * 1024 + kc0 + qW;
            #pragma unroll
            for (int i = 0; i < 8; ++i) {
                *(bf16x8*)&Wh[rW * D_STR + qW + i * 8] = *(const bf16x8*)&Wch[base + i * 8];
                *(bf16x8*)&Wl[rW * D_STR + qW + i * 8] = *(const bf16x8*)&Wcl[base + i * 8];
            }
        }
        __syncthreads();
        #pragma unroll
        for (int kc = 0; kc < 8; ++kc) {
            bf16x8 fah = *(const bf16x8*)(pAh + kc * 32);
            bf16x8 fal = *(const bf16x8*)(pAl + kc * 32);
            bf16x8 w0h = *(const bf16x8*)(pW0h + kc * 32);
            bf16x8 w0l = *(const bf16x8*)(pW0l + kc * 32);
            bf16x8 w1h = *(const bf16x8*)(pW1h + kc * 32);
            bf16x8 w1l = *(const bf16x8*)(pW1l + kc * 32);
            a0 = __builtin_amdgcn_mfma_f32_16x16x32_bf16(fal, w0h, a0, 0, 0, 0);
            a0 = __builtin_amdgcn_mfma_f32_16x16x32_bf16(fah, w0l, a0, 0, 0, 0);
            a0 = __builtin_amdgcn_mfma_f32_16x16x32_bf16(fah, w0h, a0, 0, 0, 0);
            a1 = __builtin_amdgcn_mfma_f32_16x16x32_bf16(fal, w1h, a1, 0, 0, 0);
            a1 = __builtin_amdgcn_mfma_f32_16x16x32_bf16(fah, w1l, a1, 0, 0, 0);
            a1 = __builtin_amdgcn_mfma_f32_16x16x32_bf16(fah, w1h, a1, 0, 0, 0);
        }
    }
    #pragma unroll
    for (int reg = 0; reg < 4; ++reg) {
        int prow = rt * 16 + quad * 4 + reg;
        Pre[prow * 68 + g0 * 16 + ln]       = a0[reg];
        Pre[prow * 68 + (g0 + 1) * 16 + ln] = a1[reg];
    }
    __syncthreads();

    // fused LSTM cell: thread -> (2 rows x 1 unit)
    const int jl = tid & 15;
    const int iA = (tid >> 4) * 2;
    #pragma unroll
    for (int rr = 0; rr < 2; ++rr) {
        int r = iA + rr;
        float gi = fsigmoid(Pre[r * 68 +      jl] + bsh[jl]);
        float gf = fsigmoid(Pre[r * 68 + 16 + jl] + bsh[16 + jl]);
        float gg = ftanh  (Pre[r * 68 + 32 + jl] + bsh[32 + jl]);
        float go = fsigmoid(Pre[r * 68 + 48 + jl] + bsh[48 + jl]);
        size_t ci = (size_t)(i0 + r) * 512 + j0 + jl;
        float cn = gf * c_buf[ci] + gi * gg;
        c_buf[ci] = cn;
        float h = go * ftanh(cn);
        s_buf[ci] = h;
        xc_out[(size_t)(i0 + r) * 1024 + 512 + j0 + jl] = h;
    }
}

// ---------------------------------------------------------------------------
// Logits GEMM (MFMA split-bf16): out[:, ty, :] = s @ Wfc^T + bfc.
// grid (8, 16): 32-row M-tile x 64-col N-tile. K=512, 2 chunks.
// ---------------------------------------------------------------------------
__global__ __launch_bounds__(256, 1) void logits_kernel(
    const float* __restrict__ s_buf,         // (256, 512)
    const unsigned short* __restrict__ Wfh,  // (1024, 512)
    const unsigned short* __restrict__ Wfl,
    const float* __restrict__ bfc,           // (1024,)
    float* __restrict__ out, int ty)
{
    extern __shared__ unsigned char smem_raw[];
    unsigned short* Wh = (unsigned short*)smem_raw + D_WH;
    unsigned short* Wl = (unsigned short*)smem_raw + D_WL;
    unsigned short* Ah = (unsigned short*)smem_raw + D_AH;
    unsigned short* Al = (unsigned short*)smem_raw + D_AL;

    const int tid = threadIdx.x;
    const int i0 = blockIdx.x * 32;
    const int v0 = blockIdx.y * 64;

    const int lane = tid & 63;
    const int wv   = tid >> 6;
    const int rt   = wv >> 1;
    const int ct   = wv & 1;
    const int ln   = lane & 15;
    const int quad = lane >> 4;
    const unsigned short* pAh = Ah + (rt * 16 + ln) * D_STR + quad * 8;
    const unsigned short* pAl = Al + (rt * 16 + ln) * D_STR + quad * 8;
    const unsigned short* pW0h = Wh + (ct * 32 + ln) * D_STR + quad * 8;
    const unsigned short* pW0l = Wl + (ct * 32 + ln) * D_STR + quad * 8;
    const unsigned short* pW1h = pW0h + 16 * D_STR;
    const unsigned short* pW1l = pW0l + 16 * D_STR;

    const int rW = tid >> 2;
    const int qW = (tid & 3) * 64;

    f32x4 a0 = {0.f,0.f,0.f,0.f}, a1 = {0.f,0.f,0.f,0.f};

    for (int ch = 0; ch < 2; ++ch) {
        const int kc0 = ch * 256;
        __syncthreads();
        #pragma unroll 8
        for (int r = 0; r < 32; ++r) {
            float v = s_buf[(size_t)(i0 + r) * 512 + kc0 + tid];
            unsigned short hi, lo;
            split_bf16(v, hi, lo);
            Ah[r * D_STR + tid] = hi;
            Al[r * D_STR + tid] = lo;
        }
        {
            const size_t base = (size_t)(v0 + rW) * 512 + kc0 + qW;
            #pragma unroll
            for (int i = 0; i < 8; ++i) {
                *(bf16x8*)&Wh[rW * D_STR + qW + i * 8] = *(const bf16x8*)&Wfh[base + i * 8];
                *(bf16x8*)&Wl[rW * D_STR + qW + i * 8] = *(const bf16x8*)&Wfl[base + i * 8];
            }
        }
        __syncthreads();
        #pragma unroll
        for (int kc = 0; kc < 8; ++kc) {
            bf16x8 fah = *(const bf16x8*)(pAh + kc * 32);
            bf16x8 fal = *(const bf16x8*)(pAl + kc * 32);
            bf16x8 w0h = *(const bf16x8*)(pW0h + kc * 32);
            bf16x8 w0l = *(const bf16x8*)(pW0l + kc * 32);
            bf16x8 w1h = *(const bf16x8*)(pW1h + kc * 32);
            bf16x8 w1l = *(const bf16x8*)(pW1l + kc * 32);
            a0 = __builtin_amdgcn_mfma_f32_16x16x32_bf16(fal, w0h, a0, 0, 0, 0);
            a0 = __builtin_amdgcn_mfma_f32_16x16x32_bf16(fah, w0l, a0, 0, 0, 0);
            a0 = __builtin_amdgcn_mfma_f32_16x16x32_bf16(fah, w0h, a0, 0, 0, 0);
            a1 = __builtin_amdgcn_mfma_f32_16x16x32_bf16(fal, w1h, a1, 0, 0, 0);
            a1 = __builtin_amdgcn_mfma_f32_16x16x32_bf16(fah, w1l, a1, 0, 0, 0);
            a1 = __builtin_amdgcn_mfma_f32_16x16x32_bf16(fah, w1h, a1, 0, 0, 0);
        }
    }
    // direct store: row = i0 + rt*16 + quad*4 + reg; cols v0+ct*32+ln (+16)
    #pragma unroll
    for (int reg = 0; reg < 4; ++reg) {
        int row = i0 + rt * 16 + quad * 4 + reg;
        int col0 = v0 + ct * 32 + ln;
        out[(size_t)row * (TYN * VOCAB) + ty * VOCAB + col0]      = a0[reg] + bfc[col0];
        out[(size_t)row * (TYN * VOCAB) + ty * VOCAB + col0 + 16] = a1[reg] + bfc[col0 + 16];
    }
}

// ---------------------------------------------------------------------------
// Tall-skinny: aW1[m*Tx][10] = a[m*Tx][512] @ W1[:, :512]^T + b1
// ---------------------------------------------------------------------------
__global__ __launch_bounds__(256) void attn_prep(
    const float* __restrict__ a, const float* __restrict__ W1,
    const float* __restrict__ b1, float* __restrict__ aW1)
{
    __shared__ float Wsh[10][516];
    __shared__ float red[64][10][4];
    const int tid = threadIdx.x;
    for (int idx = tid; idx < 10 * 512; idx += 256) {
        int o = idx >> 9, k = idx & 511;
        Wsh[o][k] = W1[o * 1024 + k];
    }
    __syncthreads();
    const int r = tid >> 2, kq = tid & 3;
    const float* ar = a + ((size_t)blockIdx.x * 64 + r) * 512 + kq * 128;
    float acc[10] = {};
    for (int k = 0; k < 128; k += 4) {
        float4 v = *(const float4*)&ar[k];
        #pragma unroll
        for (int o = 0; o < 10; ++o) {
            float4 w = *(const float4*)&Wsh[o][kq * 128 + k];
            acc[o] += v.x * w.x + v.y * w.y + v.z * w.z + v.w * w.w;
        }
    }
    #pragma unroll
    for (int o = 0; o < 10; ++o) red[r][o][kq] = acc[o];
    __syncthreads();
    for (int idx = tid; idx < 640; idx += 256) {
        int rr = idx / 10, o = idx % 10;
        float s = red[rr][o][0] + red[rr][o][1] + red[rr][o][2] + red[rr][o][3] + b1[o];
        aW1[((size_t)blockIdx.x * 64 + rr) * 10 + o] = s;
    }
}

// ---------------------------------------------------------------------------
// Fused attention: block per batch row i (incl. in-block sW1).
// ---------------------------------------------------------------------------
__global__ __launch_bounds__(256) void attn_kernel(
    const float* __restrict__ aW1,
    const float* __restrict__ s_buf,
    const float* __restrict__ W1,
    const float* __restrict__ W2,
    const float* __restrict__ b2,
    const float* __restrict__ a,
    float* __restrict__ xcat)
{
    __shared__ float sh_s[10];
    __shared__ float sh_w2[10];
    __shared__ float sred[160];
    __shared__ float red[256];
    __shared__ float al[256];
    const int i = blockIdx.x;
    const int tid = threadIdx.x;

    if (tid < 160) {
        int o = tid >> 4, part = tid & 15;
        const float* srow = s_buf + (size_t)i * 512;
        const float* wrow = W1 + o * 1024 + 512;
        float p = 0.f;
        for (int k = part; k < 512; k += 16) p += srow[k] * wrow[k];
        sred[tid] = p;
    }
    __syncthreads();
    if (tid < 10) {
        float v = 0.f;
        #pragma unroll
        for (int p = 0; p < 16; ++p) v += sred[tid * 16 + p];
        sh_s[tid] = v;
        sh_w2[tid] = W2[tid];
    }
    __syncthreads();

    float sum = b2[0];
    const float* ar = aW1 + ((size_t)i * TXN + tid) * 10;
    #pragma unroll
    for (int h = 0; h < 10; ++h) {
        float e = ftanh(ar[h] + sh_s[h]);
        sum += e * sh_w2[h];
    }
    float sc = fmaxf(sum, 0.f);

    red[tid] = sc;
    __syncthreads();
    for (int s = 128; s > 0; s >>= 1) {
        if (tid < s) red[tid] = fmaxf(red[tid], red[tid + s]);
        __syncthreads();
    }
    float mx = red[0];
    __syncthreads();
    float p = __expf(sc - mx);
    red[tid] = p;
    __syncthreads();
    for (int s = 128; s > 0; s >>= 1) {
        if (tid < s) red[tid] += red[tid + s];
        __syncthreads();
    }
    float inv = 1.f / red[0];
    al[tid] = p * inv;
    __syncthreads();

    float acc0 = 0.f, acc1 = 0.f;
    const float* arow = a + (size_t)i * TXN * NS;
    for (int t = 0; t < TXN; ++t) {
        float w = al[t];
        acc0 += w * arow[t * NS + tid];
        acc1 += w * arow[t * NS + 256 + tid];
    }
    xcat[(size_t)i * 1024 + tid]       = acc0;
    xcat[(size_t)i * 1024 + 256 + tid] = acc1;
}

extern "C" void kernel_launch(void* const* d_in, const int* in_sizes, int n_in,
                              void* d_out, int out_size, void* d_ws, size_t ws_size,
                              hipStream_t stream)
{
    const float* X     = (const float*)d_in[0];
    const float* Wih_f = (const float*)d_in[1];
    const float* Whh_f = (const float*)d_in[2];
    const float* b_f   = (const float*)d_in[3];
    const float* Wih_b = (const float*)d_in[4];
    const float* Whh_b = (const float*)d_in[5];
    const float* b_b   = (const float*)d_in[6];
    const float* W1    = (const float*)d_in[7];
    const float* b1    = (const float*)d_in[8];
    const float* W2    = (const float*)d_in[9];
    const float* b2    = (const float*)d_in[10];
    const float* Wc_ih = (const float*)d_in[11];
    const float* Wc_hh = (const float*)d_in[12];
    const float* bc    = (const float*)d_in[13];
    const float* Wfc   = (const float*)d_in[14];
    const float* bfc   = (const float*)d_in[15];
    float* out = (float*)d_out;
    float* ws  = (float*)d_ws;

    // workspace layout (float offsets)
    float* c_buf = ws;                    // 256*512
    float* s_buf = ws + 131072;           // 256*512
    float* xcat  = ws + 262144;           // 256*1024  [ctx | s]
    float* a     = ws + 524288;           // 256*256*512
    float* aW1   = ws + 34078720;         // 65536*10
    unsigned short* Wch = (unsigned short*)(ws + 34734080);   // 2048*1024
    unsigned short* Wcl = (unsigned short*)(ws + 35782656);   // 2048*1024
    unsigned short* Wfh = (unsigned short*)(ws + 36831232);   // 1024*512
    unsigned short* Wfl = (unsigned short*)(ws + 37093376);   // 1024*512
    unsigned int* bar = (unsigned int*)(ws + 37358080);       // 16 groups x 16 uints

    static int attrs_set = 0;
    if (!attrs_set) {
        hipFuncSetAttribute(reinterpret_cast<const void*>(encoder_kernel),
                            hipFuncAttributeMaxDynamicSharedMemorySize, ENC_LDS_BYTES);
        hipFuncSetAttribute(reinterpret_cast<const void*>(gates_kernel),
                            hipFuncAttributeMaxDynamicSharedMemorySize, DEC_LDS_BYTES);
        hipFuncSetAttribute(reinterpret_cast<const void*>(logits_kernel),
                            hipFuncAttributeMaxDynamicSharedMemorySize, DEC_LDS_BYTES);
        attrs_set = 1;
    }

    // zero c, s, xcat (contiguous 2 MB) and flag slots
    hipMemsetAsync(c_buf, 0, (size_t)524288 * sizeof(float), stream);
    hipMemsetAsync(bar, 0, 16 * 16 * sizeof(unsigned int), stream);

    wsplit_cat<<<8192, 256, 0, stream>>>(Wc_ih, Wc_hh, Wch, Wcl);
    wsplit_fc<<<2048, 256, 0, stream>>>(Wfc, Wfh, Wfl);

    // persistent bidirectional LSTM encoder
    {
        void* args[] = { (void*)&X, (void*)&Wih_f, (void*)&Whh_f, (void*)&b_f,
                         (void*)&Wih_b, (void*)&Whh_b, (void*)&b_b, (void*)&a, (void*)&bar };
        hipLaunchCooperativeKernel(reinterpret_cast<void*>(encoder_kernel),
                                   dim3(256), dim3(256), args, ENC_LDS_BYTES, stream);
    }

    attn_prep<<<1024, 256, 0, stream>>>(a, W1, b1, aW1);

    for (int ty = 0; ty < TYN; ++ty) {
        attn_kernel<<<256, 256, 0, stream>>>(aW1, s_buf, W1, W2, b2, a, xcat);
        gates_kernel<<<dim3(8, 32), 256, DEC_LDS_BYTES, stream>>>(
            xcat, Wch, Wcl, bc, c_buf, s_buf, xcat);
        logits_kernel<<<dim3(8, 16), 256, DEC_LDS_BYTES, stream>>>(
            s_buf, Wfh, Wfl, bfc, out, ty);
    }
}